// Round 2
// baseline (1093.837 us; speedup 1.0000x reference)
//
#include <hip/hip_runtime.h>
#include <hip/hip_bf16.h>

#define B_ 16
#define S_ 4096
#define O_ 512
#define D_ 128
#define NEG_INF_ -1e8f
#define MAX_ITER_ 10

typedef __attribute__((ext_vector_type(8))) short short8;
typedef __attribute__((ext_vector_type(4))) float floatx4;

__device__ inline unsigned short f32_to_bf16_rne(float x) {
    union { float f; unsigned int u; } c; c.f = x;
    unsigned int u = c.u;
    unsigned int r = (u + 0x7FFFu + ((u >> 16) & 1u)) >> 16;
    return (unsigned short)r;
}
__device__ inline float bf16_bits_to_f32(unsigned short h) {
    union { unsigned int u; float f; } c; c.u = ((unsigned int)h) << 16;
    return c.f;
}

// ---------------- init: loga from mask, zero u,v ----------------
__global__ void init_kernel(const int* __restrict__ mask,
                            float* __restrict__ u, float* __restrict__ v,
                            float* __restrict__ loga) {
    __shared__ int sc[256];
    int b = blockIdx.x, t = threadIdx.x;
    int c = 0;
    for (int k = t; k < S_; k += 256) c += (mask[(size_t)b * S_ + k] != 0);
    sc[t] = c; __syncthreads();
    for (int st = 128; st > 0; st >>= 1) { if (t < st) sc[t] += sc[t + st]; __syncthreads(); }
    if (t == 0) loga[b] = logf((float)O_ / (float)sc[0]);
    for (int k = t; k < S_; k += 256) u[(size_t)b * S_ + k] = 0.f;
    for (int k = t; k < O_; k += 256) v[b * O_ + k] = 0.f;
}

// ---------------- GEMM: KT[b][o][s] = pf*(dot(target[b,o],input[b,s]) - iou[b,s,o])/EPS ----
// one wave computes a 16(o) x 16(s) tile via split-bf16 MFMA (3 mfma per k-block)
__global__ __launch_bounds__(256) void gemm_kt(const float* __restrict__ input,
                                               const float* __restrict__ target,
                                               const float* __restrict__ iou,
                                               float* __restrict__ KT) {
    int b = blockIdx.y;
    int wid = threadIdx.x >> 6;
    int lane = threadIdx.x & 63;
    int tile = blockIdx.x * 4 + wid;      // 0 .. 8191
    int o_t = tile >> 8;                  // 0..31
    int s_t = tile & 255;                 // 0..255
    int fr  = lane & 15;                  // frag row/col index
    int kg  = lane >> 4;                  // 0..3

    const float* tgt_row = target + ((size_t)b * O_ + o_t * 16 + fr) * D_;
    const float* in_row  = input  + ((size_t)b * S_ + s_t * 16 + fr) * D_;

    floatx4 acc = {0.f, 0.f, 0.f, 0.f};
#pragma unroll
    for (int kb = 0; kb < 4; ++kb) {
        int koff = kb * 32 + kg * 8;
        short8 ahi, alo, bhi, blo;
#pragma unroll
        for (int j = 0; j < 8; ++j) {
            float x = tgt_row[koff + j];
            unsigned short h = f32_to_bf16_rne(x);
            float rem = x - bf16_bits_to_f32(h);
            ahi[j] = (short)h;
            alo[j] = (short)f32_to_bf16_rne(rem);
            float y = in_row[koff + j];
            unsigned short hb = f32_to_bf16_rne(y);
            float remb = y - bf16_bits_to_f32(hb);
            bhi[j] = (short)hb;
            blo[j] = (short)f32_to_bf16_rne(remb);
        }
        acc = __builtin_amdgcn_mfma_f32_16x16x32_bf16(alo, bhi, acc, 0, 0, 0);
        acc = __builtin_amdgcn_mfma_f32_16x16x32_bf16(ahi, blo, acc, 0, 0, 0);
        acc = __builtin_amdgcn_mfma_f32_16x16x32_bf16(ahi, bhi, acc, 0, 0, 0);
    }

    int s = s_t * 16 + fr;                 // C/D: col = lane&15  -> s
#pragma unroll
    for (int r = 0; r < 4; ++r) {
        int o = o_t * 16 + kg * 4 + r;     // C/D: row = (lane>>4)*4 + r -> o
        float d = (float)s * (1.0f / S_) - (float)o * (1.0f / O_);
        float pf = __expf(-100.0f * d * d);
        float iouv = iou[((size_t)b * S_ + s) * O_ + o];
        float val = pf * (acc[r] - iouv) * 10.0f;   // /EPS
        KT[((size_t)b * O_ + o) * S_ + s] = val;
    }
}

// ---------------- row update: u' = mask ? loga - u - LSE_o(KT[.,o,s]+v[o]) : NEG_INF ----
__global__ __launch_bounds__(256) void row_update(const float* __restrict__ KT,
                                                  const float* __restrict__ v,
                                                  float* __restrict__ u,
                                                  const int* __restrict__ mask,
                                                  const float* __restrict__ loga) {
    __shared__ float lm[256], la[256];
    int b = blockIdx.y;
    int s0 = blockIdx.x * 64;
    int t = threadIdx.x;
    int sl = t & 63, slice = t >> 6;
    const float* kt = KT + (size_t)b * O_ * S_ + (s0 + sl);
    const float* vb = v + b * O_;
    float m = -INFINITY, a = 0.f;
    int obeg = slice * 128;
#pragma unroll 4
    for (int i = 0; i < 128; ++i) {
        int o = obeg + i;
        float x = kt[(size_t)o * S_] + vb[o];
        if (x > m) { a = a * __expf(m - x) + 1.0f; m = x; }
        else       { a += __expf(x - m); }
    }
    lm[slice * 64 + sl] = m; la[slice * 64 + sl] = a;
    __syncthreads();
    if (t < 64) {
        float M = lm[t], A = la[t];
#pragma unroll
        for (int i = 1; i < 4; ++i) {
            float mi = lm[i * 64 + t], ai = la[i * 64 + t];
            float nm = fmaxf(M, mi);
            A = A * __expf(M - nm) + ai * __expf(mi - nm);
            M = nm;
        }
        float lse = M + logf(A);
        size_t si = (size_t)b * S_ + s0 + t;
        float un = mask[si] ? (loga[b] - u[si] - lse) : NEG_INF_;
        u[si] = un;
    }
}

// ---------------- col update: v' = -v - LSE_s(KT[.,o,s]+u[s]) ----------------
__global__ __launch_bounds__(256) void col_update(const float* __restrict__ KT,
                                                  const float* __restrict__ u,
                                                  float* __restrict__ v) {
    __shared__ float sm[4], sa[4];
    int b = blockIdx.y, o = blockIdx.x;
    int t = threadIdx.x;
    const float* kt = KT + ((size_t)b * O_ + o) * S_;
    const float* ub = u + (size_t)b * S_;
    float m = -INFINITY, a = 0.f;
#pragma unroll
    for (int k = 0; k < 16; ++k) {
        int s = k * 256 + t;
        float x = kt[s] + ub[s];
        if (x > m) { a = a * __expf(m - x) + 1.0f; m = x; }
        else       { a += __expf(x - m); }
    }
#pragma unroll
    for (int off = 1; off < 64; off <<= 1) {
        float mo = __shfl_xor(m, off);
        float ao = __shfl_xor(a, off);
        float nm = fmaxf(m, mo);
        a = a * __expf(m - nm) + ao * __expf(mo - nm);
        m = nm;
    }
    if ((t & 63) == 0) { sm[t >> 6] = m; sa[t >> 6] = a; }
    __syncthreads();
    if (t == 0) {
        float M = sm[0], A = sa[0];
#pragma unroll
        for (int i = 1; i < 4; ++i) {
            float nm = fmaxf(M, sm[i]);
            A = A * __expf(M - nm) + sa[i] * __expf(sm[i] - nm);
            M = nm;
        }
        float lse = M + logf(A);
        v[b * O_ + o] = -v[b * O_ + o] - lse;
    }
}

// ---------------- final: in-place out = S * exp(KT + u + v + lnpf) ----------------
__global__ __launch_bounds__(256) void final_kernel(float* __restrict__ out,
                                                    const float* __restrict__ u,
                                                    const float* __restrict__ v) {
    size_t i = (size_t)blockIdx.x * blockDim.x + threadIdx.x;
    if (i >= (size_t)B_ * O_ * S_ / 4) return;
    size_t e = i * 4;
    int b = (int)(e >> 21);            // O_*S_ = 2^21
    int rem = (int)(e & ((1u << 21) - 1));
    int o = rem >> 12;
    int s = rem & 4095;
    float4 x = *(const float4*)(out + e);
    const float* ub = u + (size_t)b * S_ + s;
    float vv = v[b * O_ + o];
    float r[4]; float xs[4] = {x.x, x.y, x.z, x.w};
#pragma unroll
    for (int j = 0; j < 4; ++j) {
        float d = (float)(s + j) * (1.0f / 4096.0f) - (float)o * (1.0f / 512.0f);
        float ln = xs[j] + ub[j] + vv - 100.0f * d * d;
        r[j] = 4096.0f * __expf(ln);
    }
    float4 res; res.x = r[0]; res.y = r[1]; res.z = r[2]; res.w = r[3];
    *(float4*)(out + e) = res;
}

extern "C" void kernel_launch(void* const* d_in, const int* in_sizes, int n_in,
                              void* d_out, int out_size, void* d_ws, size_t ws_size,
                              hipStream_t stream) {
    const float* input  = (const float*)d_in[0];
    const float* target = (const float*)d_in[1];
    const float* iou    = (const float*)d_in[2];
    const int*   mask   = (const int*)d_in[3];
    float* out  = (float*)d_out;
    float* u    = (float*)d_ws;
    float* v    = u + (size_t)B_ * S_;
    float* loga = v + (size_t)B_ * O_;

    init_kernel<<<B_, 256, 0, stream>>>(mask, u, v, loga);
    gemm_kt<<<dim3(2048, B_), 256, 0, stream>>>(input, target, iou, out);
    for (int it = 0; it < MAX_ITER_; ++it) {
        row_update<<<dim3(S_ / 64, B_), 256, 0, stream>>>(out, v, u, mask, loga);
        col_update<<<dim3(O_, B_), 256, 0, stream>>>(out, u, v);
    }
    final_kernel<<<(B_ * O_ * S_ / 4 + 255) / 256, 256, 0, stream>>>(out, u, v);
}

// Round 3
// 975.471 us; speedup vs baseline: 1.1213x; 1.1213x over previous
//
#include <hip/hip_runtime.h>
#include <hip/hip_bf16.h>

#define B_ 16
#define S_ 4096
#define O_ 512
#define D_ 128
#define NEG_INF_ -1e8f
#define MAX_ITER_ 10

typedef __attribute__((ext_vector_type(8))) short short8;
typedef __attribute__((ext_vector_type(4))) float floatx4;
typedef __attribute__((ext_vector_type(4))) unsigned short ushort4v;

__device__ inline unsigned short f32_to_bf16_rne(float x) {
    union { float f; unsigned int u; } c; c.f = x;
    unsigned int u = c.u;
    unsigned int r = (u + 0x7FFFu + ((u >> 16) & 1u)) >> 16;
    return (unsigned short)r;
}
__device__ inline float bf16_bits_to_f32(unsigned short h) {
    union { unsigned int u; float f; } c; c.u = ((unsigned int)h) << 16;
    return c.f;
}

// ---------------- init: loga from mask, zero u,v ----------------
__global__ void init_kernel(const int* __restrict__ mask,
                            float* __restrict__ u, float* __restrict__ v,
                            float* __restrict__ loga) {
    __shared__ int sc[256];
    int b = blockIdx.x, t = threadIdx.x;
    int c = 0;
    for (int k = t; k < S_; k += 256) c += (mask[(size_t)b * S_ + k] != 0);
    sc[t] = c; __syncthreads();
    for (int st = 128; st > 0; st >>= 1) { if (t < st) sc[t] += sc[t + st]; __syncthreads(); }
    if (t == 0) loga[b] = logf((float)O_ / (float)sc[0]);
    for (int k = t; k < S_; k += 256) u[(size_t)b * S_ + k] = 0.f;
    for (int k = t; k < O_; k += 256) v[b * O_ + k] = 0.f;
}

// ---------------- pre-split f32 -> bf16 hi/lo ----------------
__global__ __launch_bounds__(256) void split_kernel(const float* __restrict__ src,
                                                    unsigned short* __restrict__ hi,
                                                    unsigned short* __restrict__ lo, int n4) {
    int i = blockIdx.x * 256 + threadIdx.x;
    if (i >= n4) return;
    float4 x = ((const float4*)src)[i];
    float xs[4] = {x.x, x.y, x.z, x.w};
    ushort4v h, l;
#pragma unroll
    for (int j = 0; j < 4; ++j) {
        unsigned short hh = f32_to_bf16_rne(xs[j]);
        float rem = xs[j] - bf16_bits_to_f32(hh);
        h[j] = hh; l[j] = f32_to_bf16_rne(rem);
    }
    ((ushort4v*)hi)[i] = h;
    ((ushort4v*)lo)[i] = l;
}

// ---------------- gemm v2: 64(o) x 64(s) tile per block, iou via LDS ----------------
__global__ __launch_bounds__(256) void gemm_kt2(const unsigned short* __restrict__ in_hi,
                                                const unsigned short* __restrict__ in_lo,
                                                const unsigned short* __restrict__ tg_hi,
                                                const unsigned short* __restrict__ tg_lo,
                                                const float* __restrict__ iou,
                                                float* __restrict__ KT) {
    __shared__ float siou[64 * 65];
    int b = blockIdx.z;
    int s0 = blockIdx.x * 64;
    int o0 = blockIdx.y * 64;
    int t = threadIdx.x;

    // stage iou[b][s0..+64][o0..+64] into LDS (coalesced rows)
    {
        const float* ir = iou + ((size_t)b * S_ + s0 + (t >> 2)) * O_ + o0 + (t & 3) * 16;
        float4 q0 = ((const float4*)ir)[0];
        float4 q1 = ((const float4*)ir)[1];
        float4 q2 = ((const float4*)ir)[2];
        float4 q3 = ((const float4*)ir)[3];
        float* dst = &siou[(t >> 2) * 65 + (t & 3) * 16];
        dst[0]=q0.x; dst[1]=q0.y; dst[2]=q0.z; dst[3]=q0.w;
        dst[4]=q1.x; dst[5]=q1.y; dst[6]=q1.z; dst[7]=q1.w;
        dst[8]=q2.x; dst[9]=q2.y; dst[10]=q2.z; dst[11]=q2.w;
        dst[12]=q3.x; dst[13]=q3.y; dst[14]=q3.z; dst[15]=q3.w;
    }

    int w = t >> 6, lane = t & 63, fr = lane & 15, kg = lane >> 4;
    const unsigned short* ta_hi = tg_hi + ((size_t)b * O_ + o0 + w * 16 + fr) * D_;
    const unsigned short* ta_lo = tg_lo + ((size_t)b * O_ + o0 + w * 16 + fr) * D_;
    const unsigned short* ib_hi = in_hi + ((size_t)b * S_ + s0 + fr) * D_;
    const unsigned short* ib_lo = in_lo + ((size_t)b * S_ + s0 + fr) * D_;

    floatx4 acc[4];
#pragma unroll
    for (int st = 0; st < 4; ++st) acc[st] = (floatx4){0.f, 0.f, 0.f, 0.f};

#pragma unroll
    for (int kb = 0; kb < 4; ++kb) {
        int ko = kb * 32 + kg * 8;
        short8 ah = *(const short8*)(ta_hi + ko);
        short8 al = *(const short8*)(ta_lo + ko);
#pragma unroll
        for (int st = 0; st < 4; ++st) {
            short8 bh = *(const short8*)(ib_hi + (size_t)st * 16 * D_ + ko);
            short8 bl = *(const short8*)(ib_lo + (size_t)st * 16 * D_ + ko);
            acc[st] = __builtin_amdgcn_mfma_f32_16x16x32_bf16(al, bh, acc[st], 0, 0, 0);
            acc[st] = __builtin_amdgcn_mfma_f32_16x16x32_bf16(ah, bl, acc[st], 0, 0, 0);
            acc[st] = __builtin_amdgcn_mfma_f32_16x16x32_bf16(ah, bh, acc[st], 0, 0, 0);
        }
    }
    __syncthreads();

#pragma unroll
    for (int st = 0; st < 4; ++st) {
        int s = s0 + st * 16 + fr;
        float ds = (float)s * (1.0f / S_);
#pragma unroll
        for (int r = 0; r < 4; ++r) {
            int o = o0 + w * 16 + kg * 4 + r;
            float d = ds - (float)o * (1.0f / O_);
            float pf = __expf(-100.0f * d * d);
            float iouv = siou[(st * 16 + fr) * 65 + (w * 16 + kg * 4 + r)];
            float val = pf * (acc[st][r] - iouv) * 10.0f;
            KT[((size_t)b * O_ + o) * S_ + s] = val;
        }
    }
}

// ---------------- fallback gemm (round-2 version, no ws needed) ----------------
__global__ __launch_bounds__(256) void gemm_kt(const float* __restrict__ input,
                                               const float* __restrict__ target,
                                               const float* __restrict__ iou,
                                               float* __restrict__ KT) {
    int b = blockIdx.y;
    int wid = threadIdx.x >> 6;
    int lane = threadIdx.x & 63;
    int tile = blockIdx.x * 4 + wid;
    int o_t = tile >> 8;
    int s_t = tile & 255;
    int fr  = lane & 15;
    int kg  = lane >> 4;
    const float* tgt_row = target + ((size_t)b * O_ + o_t * 16 + fr) * D_;
    const float* in_row  = input  + ((size_t)b * S_ + s_t * 16 + fr) * D_;
    floatx4 acc = {0.f, 0.f, 0.f, 0.f};
#pragma unroll
    for (int kb = 0; kb < 4; ++kb) {
        int koff = kb * 32 + kg * 8;
        short8 ahi, alo, bhi, blo;
#pragma unroll
        for (int j = 0; j < 8; ++j) {
            float x = tgt_row[koff + j];
            unsigned short h = f32_to_bf16_rne(x);
            ahi[j] = (short)h;
            alo[j] = (short)f32_to_bf16_rne(x - bf16_bits_to_f32(h));
            float y = in_row[koff + j];
            unsigned short hb = f32_to_bf16_rne(y);
            bhi[j] = (short)hb;
            blo[j] = (short)f32_to_bf16_rne(y - bf16_bits_to_f32(hb));
        }
        acc = __builtin_amdgcn_mfma_f32_16x16x32_bf16(alo, bhi, acc, 0, 0, 0);
        acc = __builtin_amdgcn_mfma_f32_16x16x32_bf16(ahi, blo, acc, 0, 0, 0);
        acc = __builtin_amdgcn_mfma_f32_16x16x32_bf16(ahi, bhi, acc, 0, 0, 0);
    }
    int s = s_t * 16 + fr;
#pragma unroll
    for (int r = 0; r < 4; ++r) {
        int o = o_t * 16 + kg * 4 + r;
        float d = (float)s * (1.0f / S_) - (float)o * (1.0f / O_);
        float pf = __expf(-100.0f * d * d);
        float iouv = iou[((size_t)b * S_ + s) * O_ + o];
        KT[((size_t)b * O_ + o) * S_ + s] = pf * (acc[r] - iouv) * 10.0f;
    }
}

// ---------------- row update: u' = mask ? loga - u - LSE_o(KT+v) : NEG_INF ----
__global__ __launch_bounds__(256) void row_update2(const float* __restrict__ KT,
                                                   const float* __restrict__ v,
                                                   float* __restrict__ u,
                                                   const int* __restrict__ mask,
                                                   const float* __restrict__ loga) {
    __shared__ float sv[O_];
    __shared__ float lm[4][128], la[4][128];
    int b = blockIdx.y;
    int s0 = blockIdx.x * 128;
    int t = threadIdx.x, lane = t & 63, w = t >> 6;
    for (int i = t; i < O_; i += 256) sv[i] = v[b * O_ + i];
    __syncthreads();
    const float* kt = KT + (size_t)b * O_ * S_ + s0 + lane * 2;
    float m0 = -INFINITY, m1 = -INFINITY, a0 = 0.f, a1 = 0.f;
    int ob = w * 128;
#pragma unroll 8
    for (int i = 0; i < 128; ++i) {
        int o = ob + i;
        float2 x2 = *(const float2*)(kt + (size_t)o * S_);
        float vo = sv[o];
        float x0 = x2.x + vo, x1 = x2.y + vo;
        if (x0 > m0) { a0 = a0 * __expf(m0 - x0) + 1.f; m0 = x0; } else a0 += __expf(x0 - m0);
        if (x1 > m1) { a1 = a1 * __expf(m1 - x1) + 1.f; m1 = x1; } else a1 += __expf(x1 - m1);
    }
    lm[w][lane * 2] = m0;     la[w][lane * 2] = a0;
    lm[w][lane * 2 + 1] = m1; la[w][lane * 2 + 1] = a1;
    __syncthreads();
    if (t < 128) {
        float M = lm[0][t], A = la[0][t];
#pragma unroll
        for (int i = 1; i < 4; ++i) {
            float mi = lm[i][t], ai = la[i][t];
            float nm = fmaxf(M, mi);
            A = A * __expf(M - nm) + ai * __expf(mi - nm);
            M = nm;
        }
        float lse = M + logf(A);
        size_t si = (size_t)b * S_ + s0 + t;
        u[si] = mask[si] ? (loga[b] - u[si] - lse) : NEG_INF_;
    }
}

// ---------------- col update: v' = -v - LSE_s(KT+u); FIN fuses final output ----
template <int FIN>
__global__ __launch_bounds__(256) void col_update2(float* __restrict__ KT,
                                                   const float* __restrict__ u,
                                                   float* __restrict__ v) {
    __shared__ float red[8];
    int b = blockIdx.y, o = blockIdx.x;
    int t = threadIdx.x;
    float* kt = KT + ((size_t)b * O_ + o) * S_;
    const float* ub = u + (size_t)b * S_;
    float vold = v[b * O_ + o];
    float xs[16];
    float m = -INFINITY, a = 0.f;
#pragma unroll
    for (int k = 0; k < 4; ++k) {
        int s = k * 1024 + t * 4;
        float4 kx = *(const float4*)(kt + s);
        float4 ux = *(const float4*)(ub + s);
        float x0 = kx.x + ux.x, x1 = kx.y + ux.y, x2 = kx.z + ux.z, x3 = kx.w + ux.w;
        if (FIN) { xs[k*4] = x0; xs[k*4+1] = x1; xs[k*4+2] = x2; xs[k*4+3] = x3; }
        float cm = fmaxf(fmaxf(x0, x1), fmaxf(x2, x3));
        float nm = fmaxf(m, cm);
        a = a * __expf(m - nm) + __expf(x0 - nm) + __expf(x1 - nm)
                               + __expf(x2 - nm) + __expf(x3 - nm);
        m = nm;
    }
#pragma unroll
    for (int off = 1; off < 64; off <<= 1) {
        float mo = __shfl_xor(m, off), ao = __shfl_xor(a, off);
        float nm = fmaxf(m, mo);
        a = a * __expf(m - nm) + ao * __expf(mo - nm);
        m = nm;
    }
    int w = t >> 6;
    if ((t & 63) == 0) { red[w * 2] = m; red[w * 2 + 1] = a; }
    __syncthreads();
    float M = red[0], A = red[1];
#pragma unroll
    for (int i = 1; i < 4; ++i) {
        float mi = red[i * 2], ai = red[i * 2 + 1];
        float nm = fmaxf(M, mi);
        A = A * __expf(M - nm) + ai * __expf(mi - nm);
        M = nm;
    }
    float lse = M + logf(A);
    float vn = -vold - lse;
    if (t == 0) v[b * O_ + o] = vn;
    if (FIN) {
        float dovn = vn;
        float oo = (float)o * (1.0f / O_);
#pragma unroll
        for (int k = 0; k < 4; ++k) {
            int s = k * 1024 + t * 4;
            float4 r;
            float rr[4];
#pragma unroll
            for (int j = 0; j < 4; ++j) {
                float d = (float)(s + j) * (1.0f / S_) - oo;
                rr[j] = 4096.0f * __expf(xs[k * 4 + j] + dovn - 100.0f * d * d);
            }
            r.x = rr[0]; r.y = rr[1]; r.z = rr[2]; r.w = rr[3];
            *(float4*)(kt + s) = r;
        }
    }
}

extern "C" void kernel_launch(void* const* d_in, const int* in_sizes, int n_in,
                              void* d_out, int out_size, void* d_ws, size_t ws_size,
                              hipStream_t stream) {
    const float* input  = (const float*)d_in[0];
    const float* target = (const float*)d_in[1];
    const float* iou    = (const float*)d_in[2];
    const int*   mask   = (const int*)d_in[3];
    float* out  = (float*)d_out;
    float* u    = (float*)d_ws;
    float* v    = u + (size_t)B_ * S_;
    float* loga = v + (size_t)B_ * O_;

    const size_t N_IN  = (size_t)B_ * S_ * D_;   // 8388608
    const size_t N_TG  = (size_t)B_ * O_ * D_;   // 1048576
    unsigned short* in_hi = (unsigned short*)(loga + 16);
    unsigned short* in_lo = in_hi + N_IN;
    unsigned short* tg_hi = in_lo + N_IN;
    unsigned short* tg_lo = tg_hi + N_TG;
    size_t need = ((size_t)(loga + 16) - (size_t)d_ws) + (2 * N_IN + 2 * N_TG) * sizeof(unsigned short);
    bool fast = ws_size >= need;

    init_kernel<<<B_, 256, 0, stream>>>(mask, u, v, loga);
    if (fast) {
        split_kernel<<<(int)(N_IN / 4 / 256), 256, 0, stream>>>(input, in_hi, in_lo, (int)(N_IN / 4));
        split_kernel<<<(int)(N_TG / 4 / 256), 256, 0, stream>>>(target, tg_hi, tg_lo, (int)(N_TG / 4));
        gemm_kt2<<<dim3(S_ / 64, O_ / 64, B_), 256, 0, stream>>>(in_hi, in_lo, tg_hi, tg_lo, iou, out);
    } else {
        gemm_kt<<<dim3(2048, B_), 256, 0, stream>>>(input, target, iou, out);
    }
    for (int it = 0; it < MAX_ITER_; ++it) {
        row_update2<<<dim3(S_ / 128, B_), 256, 0, stream>>>(out, v, u, mask, loga);
        if (it < MAX_ITER_ - 1)
            col_update2<0><<<dim3(O_, B_), 256, 0, stream>>>(out, u, v);
        else
            col_update2<1><<<dim3(O_, B_), 256, 0, stream>>>(out, u, v);
    }
}

// Round 5
// 685.190 us; speedup vs baseline: 1.5964x; 1.4237x over previous
//
#include <hip/hip_runtime.h>
#include <hip/hip_bf16.h>

#define B_ 16
#define S_ 4096
#define O_ 512
#define D_ 128
#define NEG_INF_ -1e8f
#define MAX_ITER_ 10

typedef __attribute__((ext_vector_type(8))) short short8;
typedef __attribute__((ext_vector_type(4))) float floatx4;
typedef __attribute__((ext_vector_type(4))) unsigned short ushort4v;

__device__ inline unsigned short f32_to_bf16_rne(float x) {
    union { float f; unsigned int u; } c; c.f = x;
    unsigned int u = c.u;
    unsigned int r = (u + 0x7FFFu + ((u >> 16) & 1u)) >> 16;
    return (unsigned short)r;
}
__device__ inline float bf16_bits_to_f32(unsigned short h) {
    union { unsigned int u; float f; } c; c.u = ((unsigned int)h) << 16;
    return c.f;
}

// ---------------- init: loga from mask, zero u,v ----------------
__global__ void init_kernel(const int* __restrict__ mask,
                            float* __restrict__ u, float* __restrict__ v,
                            float* __restrict__ loga) {
    __shared__ int sc[256];
    int b = blockIdx.x, t = threadIdx.x;
    int c = 0;
    for (int k = t; k < S_; k += 256) c += (mask[(size_t)b * S_ + k] != 0);
    sc[t] = c; __syncthreads();
    for (int st = 128; st > 0; st >>= 1) { if (t < st) sc[t] += sc[t + st]; __syncthreads(); }
    if (t == 0) loga[b] = logf((float)O_ / (float)sc[0]);
    for (int k = t; k < S_; k += 256) u[(size_t)b * S_ + k] = 0.f;
    for (int k = t; k < O_; k += 256) v[b * O_ + k] = 0.f;
}

// ---------------- pre-split f32 -> bf16 hi/lo ----------------
__global__ __launch_bounds__(256) void split_kernel(const float* __restrict__ src,
                                                    unsigned short* __restrict__ hi,
                                                    unsigned short* __restrict__ lo, int n4) {
    int i = blockIdx.x * 256 + threadIdx.x;
    if (i >= n4) return;
    float4 x = ((const float4*)src)[i];
    float xs[4] = {x.x, x.y, x.z, x.w};
    ushort4v h, l;
#pragma unroll
    for (int j = 0; j < 4; ++j) {
        unsigned short hh = f32_to_bf16_rne(xs[j]);
        float rem = xs[j] - bf16_bits_to_f32(hh);
        h[j] = hh; l[j] = f32_to_bf16_rne(rem);
    }
    ((ushort4v*)hi)[i] = h;
    ((ushort4v*)lo)[i] = l;
}

// ================= FAST PATH: K in natural [b][s][o] layout in ws =================

__global__ __launch_bounds__(256) void gemm_nat(const unsigned short* __restrict__ in_hi,
                                                const unsigned short* __restrict__ in_lo,
                                                const unsigned short* __restrict__ tg_hi,
                                                const unsigned short* __restrict__ tg_lo,
                                                const float* __restrict__ iou,
                                                float* __restrict__ K) {
    int b = blockIdx.z;
    int s0 = blockIdx.x * 256;
    int o0 = blockIdx.y * 64;
    int t = threadIdx.x, wid = t >> 6, lane = t & 63, fr = lane & 15, kg = lane >> 4;
    int sw = s0 + wid * 64;

    const unsigned short* ah = in_hi + ((size_t)b * S_ + sw + fr) * D_;
    const unsigned short* al = in_lo + ((size_t)b * S_ + sw + fr) * D_;
    const unsigned short* bh = tg_hi + ((size_t)b * O_ + o0 + fr) * D_;
    const unsigned short* bl = tg_lo + ((size_t)b * O_ + o0 + fr) * D_;

    floatx4 acc[4][4];
#pragma unroll
    for (int i = 0; i < 4; ++i)
#pragma unroll
        for (int j = 0; j < 4; ++j) acc[i][j] = (floatx4){0.f, 0.f, 0.f, 0.f};

#pragma unroll
    for (int kb = 0; kb < 4; ++kb) {
        int ko = kb * 32 + kg * 8;
        short8 A_h[4], A_l[4];
#pragma unroll
        for (int i = 0; i < 4; ++i) {
            A_h[i] = *(const short8*)(ah + (size_t)i * 16 * D_ + ko);
            A_l[i] = *(const short8*)(al + (size_t)i * 16 * D_ + ko);
        }
#pragma unroll
        for (int j = 0; j < 4; ++j) {
            short8 B_h = *(const short8*)(bh + (size_t)j * 16 * D_ + ko);
            short8 B_l = *(const short8*)(bl + (size_t)j * 16 * D_ + ko);
#pragma unroll
            for (int i = 0; i < 4; ++i) {
                acc[i][j] = __builtin_amdgcn_mfma_f32_16x16x32_bf16(A_l[i], B_h, acc[i][j], 0, 0, 0);
                acc[i][j] = __builtin_amdgcn_mfma_f32_16x16x32_bf16(A_h[i], B_l, acc[i][j], 0, 0, 0);
                acc[i][j] = __builtin_amdgcn_mfma_f32_16x16x32_bf16(A_h[i], B_h, acc[i][j], 0, 0, 0);
            }
        }
    }

#pragma unroll
    for (int i = 0; i < 4; ++i) {
#pragma unroll
        for (int r = 0; r < 4; ++r) {
            int s = sw + i * 16 + kg * 4 + r;
            float sn = (float)s * (1.0f / S_);
            size_t rowb = ((size_t)b * S_ + s) * O_;
#pragma unroll
            for (int j = 0; j < 4; ++j) {
                int o = o0 + j * 16 + fr;
                float d = sn - (float)o * (1.0f / O_);
                float pf = __expf(-100.0f * d * d);
                float iouv = iou[rowb + o];
                K[rowb + o] = pf * (acc[i][j][r] - iouv) * 10.0f;
            }
        }
    }
}

// fused iteration: block = 16 s-rows x all 512 o in registers (32 f32/thread).
// phase A (row, max-guarded): u' = loga - LSE_o(K + u_old + v_old), masked.
// phase B (col partials, max-guarded): colma[(b,blk)][o] = (m, sum exp(y-m)),
//   y = K + u_new + v_old; finalize merges chunks -> v = -LSE_s.
template <int FIRST>
__global__ __launch_bounds__(256) void sink_iter(const float* __restrict__ K,
                                                 const float* __restrict__ vin,
                                                 float* __restrict__ u,
                                                 float2* __restrict__ colma,
                                                 const int* __restrict__ mask,
                                                 const float* __restrict__ loga) {
    __shared__ float sv[O_];
    __shared__ float cm[4][O_];
    __shared__ float bm[O_];
    __shared__ float ca[4][O_];
    int b = blockIdx.y;
    int t = threadIdx.x;
    int fr = t & 15, sl = t >> 4, w = t >> 6;
    if (!FIRST) {
        for (int i = t; i < O_; i += 256) sv[i] = vin[b * O_ + i];
        __syncthreads();
    }
    int s = blockIdx.x * 16 + sl;
    size_t srow = (size_t)b * S_ + s;
    const float* krow = K + srow * O_ + fr * 4;
    float uold = FIRST ? 0.f : u[srow];

    float xv[32];
#pragma unroll
    for (int k = 0; k < 8; ++k) {
        float4 q = *(const float4*)(krow + k * 64);
        if (!FIRST) {
            float4 vv = *(const float4*)&sv[fr * 4 + k * 64];
            q.x += uold + vv.x; q.y += uold + vv.y;
            q.z += uold + vv.z; q.w += uold + vv.w;
        }
        xv[k * 4 + 0] = q.x; xv[k * 4 + 1] = q.y;
        xv[k * 4 + 2] = q.z; xv[k * 4 + 3] = q.w;
    }

    // ---- phase A: row LSE (max-guarded) ----
    float M = -INFINITY;
#pragma unroll
    for (int i = 0; i < 32; ++i) M = fmaxf(M, xv[i]);
#pragma unroll
    for (int off = 1; off < 16; off <<= 1) M = fmaxf(M, __shfl_xor(M, off));
    float a = 0.f;
#pragma unroll
    for (int i = 0; i < 32; ++i) a += __expf(xv[i] - M);
#pragma unroll
    for (int off = 1; off < 16; off <<= 1) a += __shfl_xor(a, off);
    float unew = loga[b] - (M + logf(a));
    if (!mask[srow]) unew = NEG_INF_;
    if (fr == 0) u[srow] = unew;

    // ---- phase B: y = x + (unew - uold); per-column max over 16 rows, then sums ----
    float c = unew - uold;
#pragma unroll
    for (int i = 0; i < 32; ++i) xv[i] += c;

#pragma unroll
    for (int k = 0; k < 8; ++k) {
        float m0 = xv[k * 4 + 0], m1 = xv[k * 4 + 1], m2 = xv[k * 4 + 2], m3 = xv[k * 4 + 3];
        m0 = fmaxf(m0, __shfl_xor(m0, 16)); m0 = fmaxf(m0, __shfl_xor(m0, 32));
        m1 = fmaxf(m1, __shfl_xor(m1, 16)); m1 = fmaxf(m1, __shfl_xor(m1, 32));
        m2 = fmaxf(m2, __shfl_xor(m2, 16)); m2 = fmaxf(m2, __shfl_xor(m2, 32));
        m3 = fmaxf(m3, __shfl_xor(m3, 16)); m3 = fmaxf(m3, __shfl_xor(m3, 32));
        if ((t & 63) < 16) {
            float4 q; q.x = m0; q.y = m1; q.z = m2; q.w = m3;
            *(float4*)&cm[w][fr * 4 + k * 64] = q;
        }
    }
    __syncthreads();
    for (int i = t; i < O_; i += 256)
        bm[i] = fmaxf(fmaxf(cm[0][i], cm[1][i]), fmaxf(cm[2][i], cm[3][i]));
    __syncthreads();

#pragma unroll
    for (int k = 0; k < 8; ++k) {
        float4 bv = *(const float4*)&bm[fr * 4 + k * 64];
        float p0 = __expf(xv[k * 4 + 0] - bv.x);
        float p1 = __expf(xv[k * 4 + 1] - bv.y);
        float p2 = __expf(xv[k * 4 + 2] - bv.z);
        float p3 = __expf(xv[k * 4 + 3] - bv.w);
        p0 += __shfl_xor(p0, 16); p0 += __shfl_xor(p0, 32);
        p1 += __shfl_xor(p1, 16); p1 += __shfl_xor(p1, 32);
        p2 += __shfl_xor(p2, 16); p2 += __shfl_xor(p2, 32);
        p3 += __shfl_xor(p3, 16); p3 += __shfl_xor(p3, 32);
        if ((t & 63) < 16) {
            float4 q; q.x = p0; q.y = p1; q.z = p2; q.w = p3;
            *(float4*)&ca[w][fr * 4 + k * 64] = q;
        }
    }
    __syncthreads();
#pragma unroll
    for (int j = 0; j < 2; ++j) {
        int o = t + j * 256;
        float2 r;
        r.x = bm[o];
        r.y = ca[0][o] + ca[1][o] + ca[2][o] + ca[3][o];
        colma[((size_t)b * 256 + blockIdx.x) * O_ + o] = r;
    }
}

// finalize v: merge 256 (m,a) chunks per column -> v = -(M + log A)
__global__ __launch_bounds__(256) void finalize_v(const float2* __restrict__ colma,
                                                  float* __restrict__ v) {
    __shared__ float sm[4][64], sa[4][64];
    int b = blockIdx.y;
    int ol = threadIdx.x & 63, cg = threadIdx.x >> 6;
    int o = blockIdx.x * 64 + ol;
    const float2* cp = colma + (size_t)b * 256 * O_ + o;
    float M = -INFINITY, A = 0.f;
#pragma unroll 4
    for (int i = 0; i < 64; ++i) {
        float2 q = cp[(size_t)(cg * 64 + i) * O_];
        float nm = fmaxf(M, q.x);
        A = A * __expf(M - nm) + q.y * __expf(q.x - nm);
        M = nm;
    }
    sm[cg][ol] = M; sa[cg][ol] = A;
    __syncthreads();
    if (threadIdx.x < 64) {
        M = sm[0][ol]; A = sa[0][ol];
#pragma unroll
        for (int i = 1; i < 4; ++i) {
            float mi = sm[i][ol], ai = sa[i][ol];
            float nm = fmaxf(M, mi);
            A = A * __expf(M - nm) + ai * __expf(mi - nm);
            M = nm;
        }
        v[b * O_ + o] = -(M + logf(A));
    }
}

// final: out[b][o][s] = 4096 * exp(K[b][s][o] + u[s] + v[o] - 100 d^2), LDS transpose
__global__ __launch_bounds__(256) void final_tr(const float* __restrict__ K,
                                                const float* __restrict__ u,
                                                const float* __restrict__ v,
                                                float* __restrict__ out) {
    __shared__ float tile[64][65];
    __shared__ float su[64], svv[64];
    int b = blockIdx.z;
    int s0 = blockIdx.x * 64, o0 = blockIdx.y * 64;
    int t = threadIdx.x, fr = t & 15, rg = t >> 4;
    if (t < 64) su[t] = u[(size_t)b * S_ + s0 + t];
    else if (t < 128) svv[t - 64] = v[b * O_ + o0 + t - 64];
    __syncthreads();
#pragma unroll
    for (int p = 0; p < 4; ++p) {
        int sl = p * 16 + rg;
        int s = s0 + sl;
        float4 x = *(const float4*)(K + ((size_t)b * S_ + s) * O_ + o0 + fr * 4);
        float us = su[sl];
        float sn = (float)s * (1.0f / S_);
        float xs[4] = {x.x, x.y, x.z, x.w};
#pragma unroll
        for (int c = 0; c < 4; ++c) {
            int ol = fr * 4 + c;
            float d = sn - (float)(o0 + ol) * (1.0f / O_);
            tile[ol][sl] = 4096.0f * __expf(xs[c] + us + svv[ol] - 100.0f * d * d);
        }
    }
    __syncthreads();
#pragma unroll
    for (int p = 0; p < 4; ++p) {
        int ol = p * 16 + rg;
        float4 y;
        y.x = tile[ol][fr * 4 + 0];
        y.y = tile[ol][fr * 4 + 1];
        y.z = tile[ol][fr * 4 + 2];
        y.w = tile[ol][fr * 4 + 3];
        *(float4*)(out + ((size_t)b * O_ + o0 + ol) * S_ + s0 + fr * 4) = y;
    }
}

// ================= FALLBACK PATH (round-3 proven, KT in d_out) =================

__global__ __launch_bounds__(256) void gemm_kt2(const unsigned short* __restrict__ in_hi,
                                                const unsigned short* __restrict__ in_lo,
                                                const unsigned short* __restrict__ tg_hi,
                                                const unsigned short* __restrict__ tg_lo,
                                                const float* __restrict__ iou,
                                                float* __restrict__ KT) {
    __shared__ float siou[64 * 65];
    int b = blockIdx.z;
    int s0 = blockIdx.x * 64;
    int o0 = blockIdx.y * 64;
    int t = threadIdx.x;
    {
        const float* ir = iou + ((size_t)b * S_ + s0 + (t >> 2)) * O_ + o0 + (t & 3) * 16;
        float4 q0 = ((const float4*)ir)[0];
        float4 q1 = ((const float4*)ir)[1];
        float4 q2 = ((const float4*)ir)[2];
        float4 q3 = ((const float4*)ir)[3];
        float* dst = &siou[(t >> 2) * 65 + (t & 3) * 16];
        dst[0]=q0.x; dst[1]=q0.y; dst[2]=q0.z; dst[3]=q0.w;
        dst[4]=q1.x; dst[5]=q1.y; dst[6]=q1.z; dst[7]=q1.w;
        dst[8]=q2.x; dst[9]=q2.y; dst[10]=q2.z; dst[11]=q2.w;
        dst[12]=q3.x; dst[13]=q3.y; dst[14]=q3.z; dst[15]=q3.w;
    }
    int w = t >> 6, lane = t & 63, fr = lane & 15, kg = lane >> 4;
    const unsigned short* ta_hi = tg_hi + ((size_t)b * O_ + o0 + w * 16 + fr) * D_;
    const unsigned short* ta_lo = tg_lo + ((size_t)b * O_ + o0 + w * 16 + fr) * D_;
    const unsigned short* ib_hi = in_hi + ((size_t)b * S_ + s0 + fr) * D_;
    const unsigned short* ib_lo = in_lo + ((size_t)b * S_ + s0 + fr) * D_;
    floatx4 acc[4];
#pragma unroll
    for (int st = 0; st < 4; ++st) acc[st] = (floatx4){0.f, 0.f, 0.f, 0.f};
#pragma unroll
    for (int kb = 0; kb < 4; ++kb) {
        int ko = kb * 32 + kg * 8;
        short8 ah = *(const short8*)(ta_hi + ko);
        short8 al2 = *(const short8*)(ta_lo + ko);
#pragma unroll
        for (int st = 0; st < 4; ++st) {
            short8 bh2 = *(const short8*)(ib_hi + (size_t)st * 16 * D_ + ko);
            short8 bl2 = *(const short8*)(ib_lo + (size_t)st * 16 * D_ + ko);
            acc[st] = __builtin_amdgcn_mfma_f32_16x16x32_bf16(al2, bh2, acc[st], 0, 0, 0);
            acc[st] = __builtin_amdgcn_mfma_f32_16x16x32_bf16(ah, bl2, acc[st], 0, 0, 0);
            acc[st] = __builtin_amdgcn_mfma_f32_16x16x32_bf16(ah, bh2, acc[st], 0, 0, 0);
        }
    }
    __syncthreads();
#pragma unroll
    for (int st = 0; st < 4; ++st) {
        int s = s0 + st * 16 + fr;
        float ds = (float)s * (1.0f / S_);
#pragma unroll
        for (int r = 0; r < 4; ++r) {
            int o = o0 + w * 16 + kg * 4 + r;
            float d = ds - (float)o * (1.0f / O_);
            float pf = __expf(-100.0f * d * d);
            float iouv = siou[(st * 16 + fr) * 65 + (w * 16 + kg * 4 + r)];
            KT[((size_t)b * O_ + o) * S_ + s] = pf * (acc[st][r] - iouv) * 10.0f;
        }
    }
}

__global__ __launch_bounds__(256) void row_update2(const float* __restrict__ KT,
                                                   const float* __restrict__ v,
                                                   float* __restrict__ u,
                                                   const int* __restrict__ mask,
                                                   const float* __restrict__ loga) {
    __shared__ float sv[O_];
    __shared__ float lm[4][128], la[4][128];
    int b = blockIdx.y;
    int s0 = blockIdx.x * 128;
    int t = threadIdx.x, lane = t & 63, w = t >> 6;
    for (int i = t; i < O_; i += 256) sv[i] = v[b * O_ + i];
    __syncthreads();
    const float* kt = KT + (size_t)b * O_ * S_ + s0 + lane * 2;
    float m0 = -INFINITY, m1 = -INFINITY, a0 = 0.f, a1 = 0.f;
    int ob = w * 128;
#pragma unroll 8
    for (int i = 0; i < 128; ++i) {
        int o = ob + i;
        float2 x2 = *(const float2*)(kt + (size_t)o * S_);
        float vo = sv[o];
        float x0 = x2.x + vo, x1 = x2.y + vo;
        if (x0 > m0) { a0 = a0 * __expf(m0 - x0) + 1.f; m0 = x0; } else a0 += __expf(x0 - m0);
        if (x1 > m1) { a1 = a1 * __expf(m1 - x1) + 1.f; m1 = x1; } else a1 += __expf(x1 - m1);
    }
    lm[w][lane * 2] = m0;     la[w][lane * 2] = a0;
    lm[w][lane * 2 + 1] = m1; la[w][lane * 2 + 1] = a1;
    __syncthreads();
    if (t < 128) {
        float M = lm[0][t], A = la[0][t];
#pragma unroll
        for (int i = 1; i < 4; ++i) {
            float mi = lm[i][t], ai = la[i][t];
            float nm = fmaxf(M, mi);
            A = A * __expf(M - nm) + ai * __expf(mi - nm);
            M = nm;
        }
        float lse = M + logf(A);
        size_t si = (size_t)b * S_ + s0 + t;
        u[si] = mask[si] ? (loga[b] - u[si] - lse) : NEG_INF_;
    }
}

template <int FIN>
__global__ __launch_bounds__(256) void col_update2(float* __restrict__ KT,
                                                   const float* __restrict__ u,
                                                   float* __restrict__ v) {
    __shared__ float red[8];
    int b = blockIdx.y, o = blockIdx.x;
    int t = threadIdx.x;
    float* kt = KT + ((size_t)b * O_ + o) * S_;
    const float* ub = u + (size_t)b * S_;
    float vold = v[b * O_ + o];
    float xs[16];
    float m = -INFINITY, a = 0.f;
#pragma unroll
    for (int k = 0; k < 4; ++k) {
        int s = k * 1024 + t * 4;
        float4 kx = *(const float4*)(kt + s);
        float4 ux = *(const float4*)(ub + s);
        float x0 = kx.x + ux.x, x1 = kx.y + ux.y, x2 = kx.z + ux.z, x3 = kx.w + ux.w;
        if (FIN) { xs[k*4] = x0; xs[k*4+1] = x1; xs[k*4+2] = x2; xs[k*4+3] = x3; }
        float cm = fmaxf(fmaxf(x0, x1), fmaxf(x2, x3));
        float nm = fmaxf(m, cm);
        a = a * __expf(m - nm) + __expf(x0 - nm) + __expf(x1 - nm)
                               + __expf(x2 - nm) + __expf(x3 - nm);
        m = nm;
    }
#pragma unroll
    for (int off = 1; off < 64; off <<= 1) {
        float mo = __shfl_xor(m, off), ao = __shfl_xor(a, off);
        float nm = fmaxf(m, mo);
        a = a * __expf(m - nm) + ao * __expf(mo - nm);
        m = nm;
    }
    int w = t >> 6;
    if ((t & 63) == 0) { red[w * 2] = m; red[w * 2 + 1] = a; }
    __syncthreads();
    float M = red[0], A = red[1];
#pragma unroll
    for (int i = 1; i < 4; ++i) {
        float mi = red[i * 2], ai = red[i * 2 + 1];
        float nm = fmaxf(M, mi);
        A = A * __expf(M - nm) + ai * __expf(mi - nm);
        M = nm;
    }
    float lse = M + logf(A);
    float vn = -vold - lse;
    if (t == 0) v[b * O_ + o] = vn;
    if (FIN) {
        float oo = (float)o * (1.0f / O_);
#pragma unroll
        for (int k = 0; k < 4; ++k) {
            int s = k * 1024 + t * 4;
            float4 r;
            float rr[4];
#pragma unroll
            for (int j = 0; j < 4; ++j) {
                float d = (float)(s + j) * (1.0f / S_) - oo;
                rr[j] = 4096.0f * __expf(xs[k * 4 + j] + vn - 100.0f * d * d);
            }
            r.x = rr[0]; r.y = rr[1]; r.z = rr[2]; r.w = rr[3];
            *(float4*)(kt + s) = r;
        }
    }
}

// ================= launch =================

extern "C" void kernel_launch(void* const* d_in, const int* in_sizes, int n_in,
                              void* d_out, int out_size, void* d_ws, size_t ws_size,
                              hipStream_t stream) {
    const float* input  = (const float*)d_in[0];
    const float* target = (const float*)d_in[1];
    const float* iou    = (const float*)d_in[2];
    const int*   mask   = (const int*)d_in[3];
    float* out = (float*)d_out;
    float* wsf = (float*)d_ws;

    const size_t N_IN = (size_t)B_ * S_ * D_;   // 8388608
    const size_t N_TG = (size_t)B_ * O_ * D_;   // 1048576
    const size_t NK   = (size_t)B_ * S_ * O_;   // 33554432

    float* u    = wsf;                        // 65536 f
    float* v    = u + (size_t)B_ * S_;        // 8192 f
    float* loga = v + (size_t)B_ * O_;        // 16 f

    // fast-path layout: Knat, then a region shared by {bf16 splits (gemm phase)}
    // and {colma (iteration phase)} — splits are dead once gemm_nat completes.
    float* Knat = loga + 16;
    float* region = Knat + NK;
    unsigned short* f_in_hi = (unsigned short*)region;
    unsigned short* f_in_lo = f_in_hi + N_IN;
    unsigned short* f_tg_hi = f_in_lo + N_IN;
    unsigned short* f_tg_lo = f_tg_hi + N_TG;
    float2* colma = (float2*)region;          // 16*256*512 float2 = 16.8 MB (< 37.7 MB splits)
    size_t need_fast = (size_t)((char*)(f_tg_lo + N_TG) - (char*)d_ws);

    // fallback layout (round-3)
    unsigned short* m_in_hi = (unsigned short*)(loga + 16);
    unsigned short* m_in_lo = m_in_hi + N_IN;
    unsigned short* m_tg_hi = m_in_lo + N_IN;
    unsigned short* m_tg_lo = m_tg_hi + N_TG;
    size_t need_mid = (size_t)((char*)(m_tg_lo + N_TG) - (char*)d_ws);

    init_kernel<<<B_, 256, 0, stream>>>(mask, u, v, loga);

    if (ws_size >= need_fast) {
        split_kernel<<<(int)(N_IN / 4 / 256), 256, 0, stream>>>(input, f_in_hi, f_in_lo, (int)(N_IN / 4));
        split_kernel<<<(int)(N_TG / 4 / 256), 256, 0, stream>>>(target, f_tg_hi, f_tg_lo, (int)(N_TG / 4));
        gemm_nat<<<dim3(S_ / 256, O_ / 64, B_), 256, 0, stream>>>(f_in_hi, f_in_lo, f_tg_hi, f_tg_lo, iou, Knat);
        for (int it = 0; it < MAX_ITER_; ++it) {
            if (it == 0)
                sink_iter<1><<<dim3(S_ / 16, B_), 256, 0, stream>>>(Knat, v, u, colma, mask, loga);
            else
                sink_iter<0><<<dim3(S_ / 16, B_), 256, 0, stream>>>(Knat, v, u, colma, mask, loga);
            finalize_v<<<dim3(O_ / 64, B_), 256, 0, stream>>>(colma, v);
        }
        final_tr<<<dim3(S_ / 64, O_ / 64, B_), 256, 0, stream>>>(Knat, u, v, out);
    } else if (ws_size >= need_mid) {
        split_kernel<<<(int)(N_IN / 4 / 256), 256, 0, stream>>>(input, m_in_hi, m_in_lo, (int)(N_IN / 4));
        split_kernel<<<(int)(N_TG / 4 / 256), 256, 0, stream>>>(target, m_tg_hi, m_tg_lo, (int)(N_TG / 4));
        gemm_kt2<<<dim3(S_ / 64, O_ / 64, B_), 256, 0, stream>>>(m_in_hi, m_in_lo, m_tg_hi, m_tg_lo, iou, out);
        for (int it = 0; it < MAX_ITER_; ++it) {
            row_update2<<<dim3(S_ / 128, B_), 256, 0, stream>>>(out, v, u, mask, loga);
            if (it < MAX_ITER_ - 1)
                col_update2<0><<<dim3(O_, B_), 256, 0, stream>>>(out, u, v);
            else
                col_update2<1><<<dim3(O_, B_), 256, 0, stream>>>(out, u, v);
        }
    }
}

// Round 7
// 645.354 us; speedup vs baseline: 1.6949x; 1.0617x over previous
//
#include <hip/hip_runtime.h>
#include <hip/hip_bf16.h>

#define B_ 16
#define S_ 4096
#define O_ 512
#define D_ 128
#define NEG_INF_ -1e8f
#define MAX_ITER_ 10

typedef __attribute__((ext_vector_type(8))) short short8;
typedef __attribute__((ext_vector_type(4))) float floatx4;
typedef __attribute__((ext_vector_type(4))) unsigned short ushort4v;

__device__ inline unsigned short f32_to_bf16_rne(float x) {
    union { float f; unsigned int u; } c; c.f = x;
    unsigned int u = c.u;
    unsigned int r = (u + 0x7FFFu + ((u >> 16) & 1u)) >> 16;
    return (unsigned short)r;
}
__device__ inline float bf16_bits_to_f32(unsigned short h) {
    union { unsigned int u; float f; } c; c.u = ((unsigned int)h) << 16;
    return c.f;
}

// ---------------- init: loga from mask, zero u,v ----------------
__global__ void init_kernel(const int* __restrict__ mask,
                            float* __restrict__ u, float* __restrict__ v,
                            float* __restrict__ loga) {
    __shared__ int sc[256];
    int b = blockIdx.x, t = threadIdx.x;
    int c = 0;
    for (int k = t; k < S_; k += 256) c += (mask[(size_t)b * S_ + k] != 0);
    sc[t] = c; __syncthreads();
    for (int st = 128; st > 0; st >>= 1) { if (t < st) sc[t] += sc[t + st]; __syncthreads(); }
    if (t == 0) loga[b] = logf((float)O_ / (float)sc[0]);
    for (int k = t; k < S_; k += 256) u[(size_t)b * S_ + k] = 0.f;
    for (int k = t; k < O_; k += 256) v[b * O_ + k] = 0.f;
}

// ---------------- pre-split f32 -> bf16 hi/lo ----------------
__global__ __launch_bounds__(256) void split_kernel(const float* __restrict__ src,
                                                    unsigned short* __restrict__ hi,
                                                    unsigned short* __restrict__ lo, int n4) {
    int i = blockIdx.x * 256 + threadIdx.x;
    if (i >= n4) return;
    float4 x = ((const float4*)src)[i];
    float xs[4] = {x.x, x.y, x.z, x.w};
    ushort4v h, l;
#pragma unroll
    for (int j = 0; j < 4; ++j) {
        unsigned short hh = f32_to_bf16_rne(xs[j]);
        float rem = xs[j] - bf16_bits_to_f32(hh);
        h[j] = hh; l[j] = f32_to_bf16_rne(rem);
    }
    ((ushort4v*)hi)[i] = h;
    ((ushort4v*)lo)[i] = l;
}

// ================= FAST PATH =================
// K' stored pi-permuted within each aligned 64-col block:
//   K'[s][blk64 + fr*4 + j] = K[s][blk64 + j*16 + fr]  (fr 0..15, j 0..3)
// Row LSE is permutation-invariant; colma/v/sv all live consistently in
// p-space; gemm/final map real o only for the pf/d^2 term.

__global__ __launch_bounds__(256) void gemm_nat(const unsigned short* __restrict__ in_hi,
                                                const unsigned short* __restrict__ in_lo,
                                                const unsigned short* __restrict__ tg_hi,
                                                const unsigned short* __restrict__ tg_lo,
                                                const float* __restrict__ iou,
                                                float* __restrict__ K) {
    int b = blockIdx.z;
    int s0 = blockIdx.x * 256;
    int o0 = blockIdx.y * 64;
    int t = threadIdx.x, wid = t >> 6, lane = t & 63, fr = lane & 15, kg = lane >> 4;
    int sw = s0 + wid * 64;

    const unsigned short* ah = in_hi + ((size_t)b * S_ + sw + fr) * D_;
    const unsigned short* al = in_lo + ((size_t)b * S_ + sw + fr) * D_;
    const unsigned short* bh = tg_hi + ((size_t)b * O_ + o0 + fr) * D_;
    const unsigned short* bl = tg_lo + ((size_t)b * O_ + o0 + fr) * D_;

    floatx4 acc[4][4];
#pragma unroll
    for (int i = 0; i < 4; ++i)
#pragma unroll
        for (int j = 0; j < 4; ++j) acc[i][j] = (floatx4){0.f, 0.f, 0.f, 0.f};

#pragma unroll
    for (int kb = 0; kb < 4; ++kb) {
        int ko = kb * 32 + kg * 8;
        short8 A_h[4], A_l[4];
#pragma unroll
        for (int i = 0; i < 4; ++i) {
            A_h[i] = *(const short8*)(ah + (size_t)i * 16 * D_ + ko);
            A_l[i] = *(const short8*)(al + (size_t)i * 16 * D_ + ko);
        }
#pragma unroll
        for (int j = 0; j < 4; ++j) {
            short8 B_h = *(const short8*)(bh + (size_t)j * 16 * D_ + ko);
            short8 B_l = *(const short8*)(bl + (size_t)j * 16 * D_ + ko);
#pragma unroll
            for (int i = 0; i < 4; ++i) {
                acc[i][j] = __builtin_amdgcn_mfma_f32_16x16x32_bf16(A_l[i], B_h, acc[i][j], 0, 0, 0);
                acc[i][j] = __builtin_amdgcn_mfma_f32_16x16x32_bf16(A_h[i], B_l, acc[i][j], 0, 0, 0);
                acc[i][j] = __builtin_amdgcn_mfma_f32_16x16x32_bf16(A_h[i], B_h, acc[i][j], 0, 0, 0);
            }
        }
    }

#pragma unroll
    for (int i = 0; i < 4; ++i) {
#pragma unroll
        for (int r = 0; r < 4; ++r) {
            int s = sw + i * 16 + kg * 4 + r;
            float sn = (float)s * (1.0f / S_);
            size_t rowb = ((size_t)b * S_ + s) * O_;
            float tmp[4];
#pragma unroll
            for (int j = 0; j < 4; ++j) {
                int o = o0 + j * 16 + fr;
                float d = sn - (float)o * (1.0f / O_);
                float pf = __expf(-100.0f * d * d);
                float iouv = iou[rowb + o];
                tmp[j] = pf * (acc[i][j][r] - iouv) * 10.0f;
            }
            float4 q; q.x = tmp[0]; q.y = tmp[1]; q.z = tmp[2]; q.w = tmp[3];
            *(float4*)(K + rowb + o0 + fr * 4) = q;   // pi-layout dwordx4 store
        }
    }
}

// fused iteration (max-guarded BOTH phases — robust to any column magnitude):
// phase A: u' = loga - LSE_o(K+u_old+v_old), masked.
// phase B: colma[(b,blk)][p] = (m, sum exp(y-m)), y = K+u_new+v_old.
template <int FIRST>
__global__ __launch_bounds__(256) void sink_iter(const float* __restrict__ K,
                                                 const float* __restrict__ vin,
                                                 float* __restrict__ u,
                                                 float2* __restrict__ colma,
                                                 const int* __restrict__ mask,
                                                 const float* __restrict__ loga) {
    __shared__ float sv[O_];
    __shared__ float cm[4][O_];
    __shared__ float bm[O_];
    __shared__ float ca[4][O_];
    int b = blockIdx.y;
    int t = threadIdx.x;
    int fr = t & 15, sl = t >> 4, w = t >> 6;
    if (!FIRST) {
        for (int i = t; i < O_; i += 256) sv[i] = vin[b * O_ + i];
        __syncthreads();
    }
    int s = blockIdx.x * 16 + sl;
    size_t srow = (size_t)b * S_ + s;
    const float* krow = K + srow * O_ + fr * 4;
    float uold = FIRST ? 0.f : u[srow];

    float xv[32];
#pragma unroll
    for (int k = 0; k < 8; ++k) {
        float4 q = *(const float4*)(krow + k * 64);
        if (!FIRST) {
            float4 vv = *(const float4*)&sv[fr * 4 + k * 64];
            q.x += uold + vv.x; q.y += uold + vv.y;
            q.z += uold + vv.z; q.w += uold + vv.w;
        }
        xv[k * 4 + 0] = q.x; xv[k * 4 + 1] = q.y;
        xv[k * 4 + 2] = q.z; xv[k * 4 + 3] = q.w;
    }

    // ---- phase A: row LSE (max-guarded) ----
    float M = -INFINITY;
#pragma unroll
    for (int i = 0; i < 32; ++i) M = fmaxf(M, xv[i]);
#pragma unroll
    for (int off = 1; off < 16; off <<= 1) M = fmaxf(M, __shfl_xor(M, off));
    float a = 0.f;
#pragma unroll
    for (int i = 0; i < 32; ++i) a += __expf(xv[i] - M);
#pragma unroll
    for (int off = 1; off < 16; off <<= 1) a += __shfl_xor(a, off);
    float unew = loga[b] - (M + logf(a));
    if (!mask[srow]) unew = NEG_INF_;
    if (fr == 0) u[srow] = unew;

    // ---- phase B: y = x + (unew - uold); per-column max over 16 rows, then sums ----
    float c = unew - uold;
#pragma unroll
    for (int i = 0; i < 32; ++i) xv[i] += c;

#pragma unroll
    for (int k = 0; k < 8; ++k) {
        float m0 = xv[k * 4 + 0], m1 = xv[k * 4 + 1], m2 = xv[k * 4 + 2], m3 = xv[k * 4 + 3];
        m0 = fmaxf(m0, __shfl_xor(m0, 16)); m0 = fmaxf(m0, __shfl_xor(m0, 32));
        m1 = fmaxf(m1, __shfl_xor(m1, 16)); m1 = fmaxf(m1, __shfl_xor(m1, 32));
        m2 = fmaxf(m2, __shfl_xor(m2, 16)); m2 = fmaxf(m2, __shfl_xor(m2, 32));
        m3 = fmaxf(m3, __shfl_xor(m3, 16)); m3 = fmaxf(m3, __shfl_xor(m3, 32));
        if ((t & 63) < 16) {
            float4 q; q.x = m0; q.y = m1; q.z = m2; q.w = m3;
            *(float4*)&cm[w][fr * 4 + k * 64] = q;
        }
    }
    __syncthreads();
    for (int i = t; i < O_; i += 256)
        bm[i] = fmaxf(fmaxf(cm[0][i], cm[1][i]), fmaxf(cm[2][i], cm[3][i]));
    __syncthreads();

#pragma unroll
    for (int k = 0; k < 8; ++k) {
        float4 bv = *(const float4*)&bm[fr * 4 + k * 64];
        float p0 = __expf(xv[k * 4 + 0] - bv.x);
        float p1 = __expf(xv[k * 4 + 1] - bv.y);
        float p2 = __expf(xv[k * 4 + 2] - bv.z);
        float p3 = __expf(xv[k * 4 + 3] - bv.w);
        p0 += __shfl_xor(p0, 16); p0 += __shfl_xor(p0, 32);
        p1 += __shfl_xor(p1, 16); p1 += __shfl_xor(p1, 32);
        p2 += __shfl_xor(p2, 16); p2 += __shfl_xor(p2, 32);
        p3 += __shfl_xor(p3, 16); p3 += __shfl_xor(p3, 32);
        if ((t & 63) < 16) {
            float4 q; q.x = p0; q.y = p1; q.z = p2; q.w = p3;
            *(float4*)&ca[w][fr * 4 + k * 64] = q;
        }
    }
    __syncthreads();
#pragma unroll
    for (int j = 0; j < 2; ++j) {
        int o = t + j * 256;
        float2 r;
        r.x = bm[o];
        r.y = ca[0][o] + ca[1][o] + ca[2][o] + ca[3][o];
        colma[((size_t)b * 256 + blockIdx.x) * O_ + o] = r;
    }
}

// finalize v: merge 256 (m,a) chunks per column (log-space) -> v = -(M + log A)
__global__ __launch_bounds__(256) void finalize_v(const float2* __restrict__ colma,
                                                  float* __restrict__ v) {
    __shared__ float sm[4][64], sa[4][64];
    int b = blockIdx.y;
    int ol = threadIdx.x & 63, cg = threadIdx.x >> 6;
    int o = blockIdx.x * 64 + ol;
    const float2* cp = colma + (size_t)b * 256 * O_ + o;
    float M = -INFINITY, A = 0.f;
#pragma unroll 4
    for (int i = 0; i < 64; ++i) {
        float2 q = cp[(size_t)(cg * 64 + i) * O_];
        float nm = fmaxf(M, q.x);
        A = A * __expf(M - nm) + q.y * __expf(q.x - nm);
        M = nm;
    }
    sm[cg][ol] = M; sa[cg][ol] = A;
    __syncthreads();
    if (threadIdx.x < 64) {
        M = sm[0][ol]; A = sa[0][ol];
#pragma unroll
        for (int i = 1; i < 4; ++i) {
            float mi = sm[i][ol], ai = sa[i][ol];
            float nm = fmaxf(M, mi);
            A = A * __expf(M - nm) + ai * __expf(mi - nm);
            M = nm;
        }
        v[b * O_ + o] = -(M + logf(A));
    }
}

// final: out[b][o][s] = 4096*exp(K'[s][p] + u[s] + v[p] - 100 d^2), pi-aware transpose
__global__ __launch_bounds__(256) void final_tr(const float* __restrict__ K,
                                                const float* __restrict__ u,
                                                const float* __restrict__ v,
                                                float* __restrict__ out) {
    __shared__ float tile[64][65];
    __shared__ float su[64], svv[64];
    int b = blockIdx.z;
    int s0 = blockIdx.x * 64, o0 = blockIdx.y * 64;
    int t = threadIdx.x, fr = t & 15, rg = t >> 4;
    if (t < 64) su[t] = u[(size_t)b * S_ + s0 + t];
    else if (t < 128) svv[t - 64] = v[b * O_ + o0 + t - 64];   // p-space
    __syncthreads();
#pragma unroll
    for (int p = 0; p < 4; ++p) {
        int sl = p * 16 + rg;
        int s = s0 + sl;
        float4 x = *(const float4*)(K + ((size_t)b * S_ + s) * O_ + o0 + fr * 4);
        float us = su[sl];
        float sn = (float)s * (1.0f / S_);
        float xs[4] = {x.x, x.y, x.z, x.w};
#pragma unroll
        for (int c = 0; c < 4; ++c) {
            int ol = c * 16 + fr;                 // real o_local for p_l = fr*4+c
            float d = sn - (float)(o0 + ol) * (1.0f / O_);
            tile[ol][sl] = 4096.0f * __expf(xs[c] + us + svv[fr * 4 + c] - 100.0f * d * d);
        }
    }
    __syncthreads();
#pragma unroll
    for (int p = 0; p < 4; ++p) {
        int ol = p * 16 + rg;
        float4 y;
        y.x = tile[ol][fr * 4 + 0];
        y.y = tile[ol][fr * 4 + 1];
        y.z = tile[ol][fr * 4 + 2];
        y.w = tile[ol][fr * 4 + 3];
        *(float4*)(out + ((size_t)b * O_ + o0 + ol) * S_ + s0 + fr * 4) = y;
    }
}

// ================= FALLBACK PATH (round-3 proven, KT in d_out) =================

__global__ __launch_bounds__(256) void gemm_kt2(const unsigned short* __restrict__ in_hi,
                                                const unsigned short* __restrict__ in_lo,
                                                const unsigned short* __restrict__ tg_hi,
                                                const unsigned short* __restrict__ tg_lo,
                                                const float* __restrict__ iou,
                                                float* __restrict__ KT) {
    __shared__ float siou[64 * 65];
    int b = blockIdx.z;
    int s0 = blockIdx.x * 64;
    int o0 = blockIdx.y * 64;
    int t = threadIdx.x;
    {
        const float* ir = iou + ((size_t)b * S_ + s0 + (t >> 2)) * O_ + o0 + (t & 3) * 16;
        float4 q0 = ((const float4*)ir)[0];
        float4 q1 = ((const float4*)ir)[1];
        float4 q2 = ((const float4*)ir)[2];
        float4 q3 = ((const float4*)ir)[3];
        float* dst = &siou[(t >> 2) * 65 + (t & 3) * 16];
        dst[0]=q0.x; dst[1]=q0.y; dst[2]=q0.z; dst[3]=q0.w;
        dst[4]=q1.x; dst[5]=q1.y; dst[6]=q1.z; dst[7]=q1.w;
        dst[8]=q2.x; dst[9]=q2.y; dst[10]=q2.z; dst[11]=q2.w;
        dst[12]=q3.x; dst[13]=q3.y; dst[14]=q3.z; dst[15]=q3.w;
    }
    int w = t >> 6, lane = t & 63, fr = lane & 15, kg = lane >> 4;
    const unsigned short* ta_hi = tg_hi + ((size_t)b * O_ + o0 + w * 16 + fr) * D_;
    const unsigned short* ta_lo = tg_lo + ((size_t)b * O_ + o0 + w * 16 + fr) * D_;
    const unsigned short* ib_hi = in_hi + ((size_t)b * S_ + s0 + fr) * D_;
    const unsigned short* ib_lo = in_lo + ((size_t)b * S_ + s0 + fr) * D_;
    floatx4 acc[4];
#pragma unroll
    for (int st = 0; st < 4; ++st) acc[st] = (floatx4){0.f, 0.f, 0.f, 0.f};
#pragma unroll
    for (int kb = 0; kb < 4; ++kb) {
        int ko = kb * 32 + kg * 8;
        short8 ah = *(const short8*)(ta_hi + ko);
        short8 al2 = *(const short8*)(ta_lo + ko);
#pragma unroll
        for (int st = 0; st < 4; ++st) {
            short8 bh2 = *(const short8*)(ib_hi + (size_t)st * 16 * D_ + ko);
            short8 bl2 = *(const short8*)(ib_lo + (size_t)st * 16 * D_ + ko);
            acc[st] = __builtin_amdgcn_mfma_f32_16x16x32_bf16(al2, bh2, acc[st], 0, 0, 0);
            acc[st] = __builtin_amdgcn_mfma_f32_16x16x32_bf16(ah, bl2, acc[st], 0, 0, 0);
            acc[st] = __builtin_amdgcn_mfma_f32_16x16x32_bf16(ah, bh2, acc[st], 0, 0, 0);
        }
    }
    __syncthreads();
#pragma unroll
    for (int st = 0; st < 4; ++st) {
        int s = s0 + st * 16 + fr;
        float ds = (float)s * (1.0f / S_);
#pragma unroll
        for (int r = 0; r < 4; ++r) {
            int o = o0 + w * 16 + kg * 4 + r;
            float d = ds - (float)o * (1.0f / O_);
            float pf = __expf(-100.0f * d * d);
            float iouv = siou[(st * 16 + fr) * 65 + (w * 16 + kg * 4 + r)];
            KT[((size_t)b * O_ + o) * S_ + s] = pf * (acc[st][r] - iouv) * 10.0f;
        }
    }
}

__global__ __launch_bounds__(256) void row_update2(const float* __restrict__ KT,
                                                   const float* __restrict__ v,
                                                   float* __restrict__ u,
                                                   const int* __restrict__ mask,
                                                   const float* __restrict__ loga) {
    __shared__ float sv[O_];
    __shared__ float lm[4][128], la[4][128];
    int b = blockIdx.y;
    int s0 = blockIdx.x * 128;
    int t = threadIdx.x, lane = t & 63, w = t >> 6;
    for (int i = t; i < O_; i += 256) sv[i] = v[b * O_ + i];
    __syncthreads();
    const float* kt = KT + (size_t)b * O_ * S_ + s0 + lane * 2;
    float m0 = -INFINITY, m1 = -INFINITY, a0 = 0.f, a1 = 0.f;
    int ob = w * 128;
#pragma unroll 8
    for (int i = 0; i < 128; ++i) {
        int o = ob + i;
        float2 x2 = *(const float2*)(kt + (size_t)o * S_);
        float vo = sv[o];
        float x0 = x2.x + vo, x1 = x2.y + vo;
        if (x0 > m0) { a0 = a0 * __expf(m0 - x0) + 1.f; m0 = x0; } else a0 += __expf(x0 - m0);
        if (x1 > m1) { a1 = a1 * __expf(m1 - x1) + 1.f; m1 = x1; } else a1 += __expf(x1 - m1);
    }
    lm[w][lane * 2] = m0;     la[w][lane * 2] = a0;
    lm[w][lane * 2 + 1] = m1; la[w][lane * 2 + 1] = a1;
    __syncthreads();
    if (t < 128) {
        float M = lm[0][t], A = la[0][t];
#pragma unroll
        for (int i = 1; i < 4; ++i) {
            float mi = lm[i][t], ai = la[i][t];
            float nm = fmaxf(M, mi);
            A = A * __expf(M - nm) + ai * __expf(mi - nm);
            M = nm;
        }
        float lse = M + logf(A);
        size_t si = (size_t)b * S_ + s0 + t;
        u[si] = mask[si] ? (loga[b] - u[si] - lse) : NEG_INF_;
    }
}

template <int FIN>
__global__ __launch_bounds__(256) void col_update2(float* __restrict__ KT,
                                                   const float* __restrict__ u,
                                                   float* __restrict__ v) {
    __shared__ float red[8];
    int b = blockIdx.y, o = blockIdx.x;
    int t = threadIdx.x;
    float* kt = KT + ((size_t)b * O_ + o) * S_;
    const float* ub = u + (size_t)b * S_;
    float vold = v[b * O_ + o];
    float xs[16];
    float m = -INFINITY, a = 0.f;
#pragma unroll
    for (int k = 0; k < 4; ++k) {
        int s = k * 1024 + t * 4;
        float4 kx = *(const float4*)(kt + s);
        float4 ux = *(const float4*)(ub + s);
        float x0 = kx.x + ux.x, x1 = kx.y + ux.y, x2 = kx.z + ux.z, x3 = kx.w + ux.w;
        if (FIN) { xs[k*4] = x0; xs[k*4+1] = x1; xs[k*4+2] = x2; xs[k*4+3] = x3; }
        float cm = fmaxf(fmaxf(x0, x1), fmaxf(x2, x3));
        float nm = fmaxf(m, cm);
        a = a * __expf(m - nm) + __expf(x0 - nm) + __expf(x1 - nm)
                               + __expf(x2 - nm) + __expf(x3 - nm);
        m = nm;
    }
#pragma unroll
    for (int off = 1; off < 64; off <<= 1) {
        float mo = __shfl_xor(m, off), ao = __shfl_xor(a, off);
        float nm = fmaxf(m, mo);
        a = a * __expf(m - nm) + ao * __expf(mo - nm);
        m = nm;
    }
    int w = t >> 6;
    if ((t & 63) == 0) { red[w * 2] = m; red[w * 2 + 1] = a; }
    __syncthreads();
    float M = red[0], A = red[1];
#pragma unroll
    for (int i = 1; i < 4; ++i) {
        float mi = red[i * 2], ai = red[i * 2 + 1];
        float nm = fmaxf(M, mi);
        A = A * __expf(M - nm) + ai * __expf(mi - nm);
        M = nm;
    }
    float lse = M + logf(A);
    float vn = -vold - lse;
    if (t == 0) v[b * O_ + o] = vn;
    if (FIN) {
        float oo = (float)o * (1.0f / O_);
#pragma unroll
        for (int k = 0; k < 4; ++k) {
            int s = k * 1024 + t * 4;
            float4 r;
            float rr[4];
#pragma unroll
            for (int j = 0; j < 4; ++j) {
                float d = (float)(s + j) * (1.0f / S_) - oo;
                rr[j] = 4096.0f * __expf(xs[k * 4 + j] + vn - 100.0f * d * d);
            }
            r.x = rr[0]; r.y = rr[1]; r.z = rr[2]; r.w = rr[3];
            *(float4*)(kt + s) = r;
        }
    }
}

// ================= launch =================

extern "C" void kernel_launch(void* const* d_in, const int* in_sizes, int n_in,
                              void* d_out, int out_size, void* d_ws, size_t ws_size,
                              hipStream_t stream) {
    const float* input  = (const float*)d_in[0];
    const float* target = (const float*)d_in[1];
    const float* iou    = (const float*)d_in[2];
    const int*   mask   = (const int*)d_in[3];
    float* out = (float*)d_out;
    float* wsf = (float*)d_ws;

    const size_t N_IN = (size_t)B_ * S_ * D_;   // 8388608
    const size_t N_TG = (size_t)B_ * O_ * D_;   // 1048576
    const size_t NK   = (size_t)B_ * S_ * O_;   // 33554432

    float* u    = wsf;
    float* v    = u + (size_t)B_ * S_;
    float* loga = v + (size_t)B_ * O_;

    float* Knat = loga + 16;
    float* region = Knat + NK;
    unsigned short* f_in_hi = (unsigned short*)region;
    unsigned short* f_in_lo = f_in_hi + N_IN;
    unsigned short* f_tg_hi = f_in_lo + N_IN;
    unsigned short* f_tg_lo = f_tg_hi + N_TG;
    float2* colma = (float2*)region;          // aliases dead split arrays
    size_t need_fast = (size_t)((char*)(f_tg_lo + N_TG) - (char*)d_ws);

    unsigned short* m_in_hi = (unsigned short*)(loga + 16);
    unsigned short* m_in_lo = m_in_hi + N_IN;
    unsigned short* m_tg_hi = m_in_lo + N_IN;
    unsigned short* m_tg_lo = m_tg_hi + N_TG;
    size_t need_mid = (size_t)((char*)(m_tg_lo + N_TG) - (char*)d_ws);

    init_kernel<<<B_, 256, 0, stream>>>(mask, u, v, loga);

    if (ws_size >= need_fast) {
        split_kernel<<<(int)(N_IN / 4 / 256), 256, 0, stream>>>(input, f_in_hi, f_in_lo, (int)(N_IN / 4));
        split_kernel<<<(int)(N_TG / 4 / 256), 256, 0, stream>>>(target, f_tg_hi, f_tg_lo, (int)(N_TG / 4));
        gemm_nat<<<dim3(S_ / 256, O_ / 64, B_), 256, 0, stream>>>(f_in_hi, f_in_lo, f_tg_hi, f_tg_lo, iou, Knat);
        for (int it = 0; it < MAX_ITER_; ++it) {
            if (it == 0)
                sink_iter<1><<<dim3(S_ / 16, B_), 256, 0, stream>>>(Knat, v, u, colma, mask, loga);
            else
                sink_iter<0><<<dim3(S_ / 16, B_), 256, 0, stream>>>(Knat, v, u, colma, mask, loga);
            finalize_v<<<dim3(O_ / 64, B_), 256, 0, stream>>>(colma, v);
        }
        final_tr<<<dim3(S_ / 64, O_ / 64, B_), 256, 0, stream>>>(Knat, u, v, out);
    } else if (ws_size >= need_mid) {
        split_kernel<<<(int)(N_IN / 4 / 256), 256, 0, stream>>>(input, m_in_hi, m_in_lo, (int)(N_IN / 4));
        split_kernel<<<(int)(N_TG / 4 / 256), 256, 0, stream>>>(target, m_tg_hi, m_tg_lo, (int)(N_TG / 4));
        gemm_kt2<<<dim3(S_ / 64, O_ / 64, B_), 256, 0, stream>>>(m_in_hi, m_in_lo, m_tg_hi, m_tg_lo, iou, out);
        for (int it = 0; it < MAX_ITER_; ++it) {
            row_update2<<<dim3(S_ / 128, B_), 256, 0, stream>>>(out, v, u, mask, loga);
            if (it < MAX_ITER_ - 1)
                col_update2<0><<<dim3(O_, B_), 256, 0, stream>>>(out, u, v);
            else
                col_update2<1><<<dim3(O_, B_), 256, 0, stream>>>(out, u, v);
        }
    }
}

// Round 8
// 513.399 us; speedup vs baseline: 2.1306x; 1.2570x over previous
//
#include <hip/hip_runtime.h>
#include <hip/hip_bf16.h>

#define B_ 16
#define S_ 4096
#define O_ 512
#define D_ 128
#define NEG_INF_ -1e8f
#define MAX_ITER_ 10
#define YST 513

typedef __attribute__((ext_vector_type(8))) short short8;
typedef __attribute__((ext_vector_type(4))) float floatx4;
typedef __attribute__((ext_vector_type(4))) unsigned short ushort4v;

__device__ inline unsigned short f32_to_bf16_rne(float x) {
    union { float f; unsigned int u; } c; c.f = x;
    unsigned int u = c.u;
    unsigned int r = (u + 0x7FFFu + ((u >> 16) & 1u)) >> 16;
    return (unsigned short)r;
}
__device__ inline float bf16_bits_to_f32(unsigned short h) {
    union { unsigned int u; float f; } c; c.u = ((unsigned int)h) << 16;
    return c.f;
}

// ---------------- init: loga from mask, zero u,v ----------------
__global__ void init_kernel(const int* __restrict__ mask,
                            float* __restrict__ u, float* __restrict__ v,
                            float* __restrict__ loga) {
    __shared__ int sc[256];
    int b = blockIdx.x, t = threadIdx.x;
    int c = 0;
    for (int k = t; k < S_; k += 256) c += (mask[(size_t)b * S_ + k] != 0);
    sc[t] = c; __syncthreads();
    for (int st = 128; st > 0; st >>= 1) { if (t < st) sc[t] += sc[t + st]; __syncthreads(); }
    if (t == 0) loga[b] = logf((float)O_ / (float)sc[0]);
    for (int k = t; k < S_; k += 256) u[(size_t)b * S_ + k] = 0.f;
    for (int k = t; k < O_; k += 256) v[b * O_ + k] = 0.f;
}

// ---------------- pre-split f32 -> bf16 hi/lo ----------------
__global__ __launch_bounds__(256) void split_kernel(const float* __restrict__ src,
                                                    unsigned short* __restrict__ hi,
                                                    unsigned short* __restrict__ lo, int n4) {
    int i = blockIdx.x * 256 + threadIdx.x;
    if (i >= n4) return;
    float4 x = ((const float4*)src)[i];
    float xs[4] = {x.x, x.y, x.z, x.w};
    ushort4v h, l;
#pragma unroll
    for (int j = 0; j < 4; ++j) {
        unsigned short hh = f32_to_bf16_rne(xs[j]);
        float rem = xs[j] - bf16_bits_to_f32(hh);
        h[j] = hh; l[j] = f32_to_bf16_rne(rem);
    }
    ((ushort4v*)hi)[i] = h;
    ((ushort4v*)lo)[i] = l;
}

// ================= FAST PATH (natural K[b][s][o] layout) =================
// gemm v3: A-operand = target (o rows), B-operand = input (s cols).
// C/D: row = o (kg*4+r contiguous in o!), col = s. So each lane's 4 acc regs
// line up with 4 consecutive real o -> iou loads and K stores are dwordx4.

__global__ __launch_bounds__(256) void gemm_nat(const unsigned short* __restrict__ in_hi,
                                                const unsigned short* __restrict__ in_lo,
                                                const unsigned short* __restrict__ tg_hi,
                                                const unsigned short* __restrict__ tg_lo,
                                                const float* __restrict__ iou,
                                                float* __restrict__ K) {
    int b = blockIdx.z;
    int s0 = blockIdx.x * 256;
    int o0 = blockIdx.y * 64;
    int t = threadIdx.x, wid = t >> 6, lane = t & 63, fr = lane & 15, kg = lane >> 4;
    int sw = s0 + wid * 64;

    const unsigned short* ih = in_hi + ((size_t)b * S_ + sw + fr) * D_;
    const unsigned short* il = in_lo + ((size_t)b * S_ + sw + fr) * D_;
    const unsigned short* th = tg_hi + ((size_t)b * O_ + o0 + fr) * D_;
    const unsigned short* tl = tg_lo + ((size_t)b * O_ + o0 + fr) * D_;

    floatx4 acc[4][4];   // [i: s-frag][j: o-frag]
#pragma unroll
    for (int i = 0; i < 4; ++i)
#pragma unroll
        for (int j = 0; j < 4; ++j) acc[i][j] = (floatx4){0.f, 0.f, 0.f, 0.f};

#pragma unroll
    for (int kb = 0; kb < 4; ++kb) {
        int ko = kb * 32 + kg * 8;
        short8 T_h[4], T_l[4];
#pragma unroll
        for (int j = 0; j < 4; ++j) {
            T_h[j] = *(const short8*)(th + (size_t)j * 16 * D_ + ko);
            T_l[j] = *(const short8*)(tl + (size_t)j * 16 * D_ + ko);
        }
#pragma unroll
        for (int i = 0; i < 4; ++i) {
            short8 I_h = *(const short8*)(ih + (size_t)i * 16 * D_ + ko);
            short8 I_l = *(const short8*)(il + (size_t)i * 16 * D_ + ko);
#pragma unroll
            for (int j = 0; j < 4; ++j) {
                acc[i][j] = __builtin_amdgcn_mfma_f32_16x16x32_bf16(T_l[j], I_h, acc[i][j], 0, 0, 0);
                acc[i][j] = __builtin_amdgcn_mfma_f32_16x16x32_bf16(T_h[j], I_l, acc[i][j], 0, 0, 0);
                acc[i][j] = __builtin_amdgcn_mfma_f32_16x16x32_bf16(T_h[j], I_h, acc[i][j], 0, 0, 0);
            }
        }
    }

#pragma unroll
    for (int i = 0; i < 4; ++i) {
        int s = sw + i * 16 + fr;
        float sn = (float)s * (1.0f / S_);
        size_t rowb = ((size_t)b * S_ + s) * O_;
#pragma unroll
        for (int j = 0; j < 4; ++j) {
            int ob = o0 + j * 16 + kg * 4;
            float4 iv = *(const float4*)(iou + rowb + ob);
            float ivs[4] = {iv.x, iv.y, iv.z, iv.w};
            float tmp[4];
#pragma unroll
            for (int r = 0; r < 4; ++r) {
                float d = sn - (float)(ob + r) * (1.0f / O_);
                float pf = __expf(-100.0f * d * d);
                tmp[r] = pf * (acc[i][j][r] - ivs[r]) * 10.0f;
            }
            float4 q; q.x = tmp[0]; q.y = tmp[1]; q.z = tmp[2]; q.w = tmp[3];
            *(float4*)(K + rowb + ob) = q;
        }
    }
}

// fused iteration, LDS-transpose phase B (same max-guarded semantics as r7):
// phase A (row threads): u' = loga - LSE_o(K+u_old+v_old), masked.
// write y = K+u'+v_old to LDS tile [16][513]; barrier;
// phase B (col threads): per column o in {t, t+256}: m = max_r y, a = sum exp(y-m);
// colma[(b,blk)][o] = (m, a). finalize merges 256 chunks in log space.
template <int FIRST>
__global__ __launch_bounds__(256) void sink_iter(const float* __restrict__ K,
                                                 const float* __restrict__ vin,
                                                 float* __restrict__ u,
                                                 float2* __restrict__ colma,
                                                 const int* __restrict__ mask,
                                                 const float* __restrict__ loga) {
    __shared__ float sv[O_];
    __shared__ float sy[16 * YST];
    int b = blockIdx.y;
    int t = threadIdx.x;
    int fr = t & 15, sl = t >> 4;
    if (!FIRST) {
        for (int i = t; i < O_; i += 256) sv[i] = vin[b * O_ + i];
        __syncthreads();
    }
    int s = blockIdx.x * 16 + sl;
    size_t srow = (size_t)b * S_ + s;
    const float* krow = K + srow * O_ + fr * 4;
    float uold = FIRST ? 0.f : u[srow];

    float xv[32];
#pragma unroll
    for (int k = 0; k < 8; ++k) {
        float4 q = *(const float4*)(krow + k * 64);
        if (!FIRST) {
            float4 vv = *(const float4*)&sv[fr * 4 + k * 64];
            q.x += uold + vv.x; q.y += uold + vv.y;
            q.z += uold + vv.z; q.w += uold + vv.w;
        }
        xv[k * 4 + 0] = q.x; xv[k * 4 + 1] = q.y;
        xv[k * 4 + 2] = q.z; xv[k * 4 + 3] = q.w;
    }

    // ---- phase A: row LSE (max-guarded), 16 lanes per row ----
    float M = -INFINITY;
#pragma unroll
    for (int i = 0; i < 32; ++i) M = fmaxf(M, xv[i]);
#pragma unroll
    for (int off = 1; off < 16; off <<= 1) M = fmaxf(M, __shfl_xor(M, off));
    float a = 0.f;
#pragma unroll
    for (int i = 0; i < 32; ++i) a += __expf(xv[i] - M);
#pragma unroll
    for (int off = 1; off < 16; off <<= 1) a += __shfl_xor(a, off);
    float unew = loga[b] - (M + logf(a));
    if (!mask[srow]) unew = NEG_INF_;
    if (fr == 0) u[srow] = unew;

    // ---- write y = x + (unew - uold) to LDS ----
    float c = unew - uold;
#pragma unroll
    for (int k = 0; k < 8; ++k) {
        float4 q;
        q.x = xv[k * 4 + 0] + c; q.y = xv[k * 4 + 1] + c;
        q.z = xv[k * 4 + 2] + c; q.w = xv[k * 4 + 3] + c;
        *(float4*)&sy[sl * YST + fr * 4 + k * 64] = q;
    }
    __syncthreads();

    // ---- phase B: per-column (max, sum) over the 16 rows ----
    float2* cout = colma + ((size_t)b * 256 + blockIdx.x) * O_;
#pragma unroll
    for (int h = 0; h < 2; ++h) {
        int o = t + h * 256;
        float q[16];
        float m = -INFINITY;
#pragma unroll
        for (int r = 0; r < 16; ++r) { q[r] = sy[r * YST + o]; m = fmaxf(m, q[r]); }
        float aa = 0.f;
#pragma unroll
        for (int r = 0; r < 16; ++r) aa += __expf(q[r] - m);
        float2 res; res.x = m; res.y = aa;
        cout[o] = res;
    }
}

// finalize v: merge 256 (m,a) chunks per column (log-space) -> v = -(M + log A)
__global__ __launch_bounds__(256) void finalize_v(const float2* __restrict__ colma,
                                                  float* __restrict__ v) {
    __shared__ float sm[4][64], sa[4][64];
    int b = blockIdx.y;
    int ol = threadIdx.x & 63, cg = threadIdx.x >> 6;
    int o = blockIdx.x * 64 + ol;
    const float2* cp = colma + (size_t)b * 256 * O_ + o;
    float M = -INFINITY, A = 0.f;
#pragma unroll 4
    for (int i = 0; i < 64; ++i) {
        float2 q = cp[(size_t)(cg * 64 + i) * O_];
        float nm = fmaxf(M, q.x);
        A = A * __expf(M - nm) + q.y * __expf(q.x - nm);
        M = nm;
    }
    sm[cg][ol] = M; sa[cg][ol] = A;
    __syncthreads();
    if (threadIdx.x < 64) {
        M = sm[0][ol]; A = sa[0][ol];
#pragma unroll
        for (int i = 1; i < 4; ++i) {
            float mi = sm[i][ol], ai = sa[i][ol];
            float nm = fmaxf(M, mi);
            A = A * __expf(M - nm) + ai * __expf(mi - nm);
            M = nm;
        }
        v[b * O_ + o] = -(M + logf(A));
    }
}

// final: out[b][o][s] = 4096*exp(K[b][s][o] + u[s] + v[o] - 100 d^2), LDS transpose
__global__ __launch_bounds__(256) void final_tr(const float* __restrict__ K,
                                                const float* __restrict__ u,
                                                const float* __restrict__ v,
                                                float* __restrict__ out) {
    __shared__ float tile[64][65];
    __shared__ float su[64], svv[64];
    int b = blockIdx.z;
    int s0 = blockIdx.x * 64, o0 = blockIdx.y * 64;
    int t = threadIdx.x, fr = t & 15, rg = t >> 4;
    if (t < 64) su[t] = u[(size_t)b * S_ + s0 + t];
    else if (t < 128) svv[t - 64] = v[b * O_ + o0 + t - 64];
    __syncthreads();
#pragma unroll
    for (int p = 0; p < 4; ++p) {
        int sl = p * 16 + rg;
        int s = s0 + sl;
        float4 x = *(const float4*)(K + ((size_t)b * S_ + s) * O_ + o0 + fr * 4);
        float us = su[sl];
        float sn = (float)s * (1.0f / S_);
        float xs[4] = {x.x, x.y, x.z, x.w};
#pragma unroll
        for (int c = 0; c < 4; ++c) {
            int ol = fr * 4 + c;
            float d = sn - (float)(o0 + ol) * (1.0f / O_);
            tile[ol][sl] = 4096.0f * __expf(xs[c] + us + svv[ol] - 100.0f * d * d);
        }
    }
    __syncthreads();
#pragma unroll
    for (int p = 0; p < 4; ++p) {
        int ol = p * 16 + rg;
        float4 y;
        y.x = tile[ol][fr * 4 + 0];
        y.y = tile[ol][fr * 4 + 1];
        y.z = tile[ol][fr * 4 + 2];
        y.w = tile[ol][fr * 4 + 3];
        *(float4*)(out + ((size_t)b * O_ + o0 + ol) * S_ + s0 + fr * 4) = y;
    }
}

// ================= FALLBACK PATH (round-3 proven, KT in d_out) =================

__global__ __launch_bounds__(256) void gemm_kt2(const unsigned short* __restrict__ in_hi,
                                                const unsigned short* __restrict__ in_lo,
                                                const unsigned short* __restrict__ tg_hi,
                                                const unsigned short* __restrict__ tg_lo,
                                                const float* __restrict__ iou,
                                                float* __restrict__ KT) {
    __shared__ float siou[64 * 65];
    int b = blockIdx.z;
    int s0 = blockIdx.x * 64;
    int o0 = blockIdx.y * 64;
    int t = threadIdx.x;
    {
        const float* ir = iou + ((size_t)b * S_ + s0 + (t >> 2)) * O_ + o0 + (t & 3) * 16;
        float4 q0 = ((const float4*)ir)[0];
        float4 q1 = ((const float4*)ir)[1];
        float4 q2 = ((const float4*)ir)[2];
        float4 q3 = ((const float4*)ir)[3];
        float* dst = &siou[(t >> 2) * 65 + (t & 3) * 16];
        dst[0]=q0.x; dst[1]=q0.y; dst[2]=q0.z; dst[3]=q0.w;
        dst[4]=q1.x; dst[5]=q1.y; dst[6]=q1.z; dst[7]=q1.w;
        dst[8]=q2.x; dst[9]=q2.y; dst[10]=q2.z; dst[11]=q2.w;
        dst[12]=q3.x; dst[13]=q3.y; dst[14]=q3.z; dst[15]=q3.w;
    }
    int w = t >> 6, lane = t & 63, fr = lane & 15, kg = lane >> 4;
    const unsigned short* ta_hi = tg_hi + ((size_t)b * O_ + o0 + w * 16 + fr) * D_;
    const unsigned short* ta_lo = tg_lo + ((size_t)b * O_ + o0 + w * 16 + fr) * D_;
    const unsigned short* ib_hi = in_hi + ((size_t)b * S_ + s0 + fr) * D_;
    const unsigned short* ib_lo = in_lo + ((size_t)b * S_ + s0 + fr) * D_;
    floatx4 acc[4];
#pragma unroll
    for (int st = 0; st < 4; ++st) acc[st] = (floatx4){0.f, 0.f, 0.f, 0.f};
#pragma unroll
    for (int kb = 0; kb < 4; ++kb) {
        int ko = kb * 32 + kg * 8;
        short8 ah = *(const short8*)(ta_hi + ko);
        short8 al2 = *(const short8*)(ta_lo + ko);
#pragma unroll
        for (int st = 0; st < 4; ++st) {
            short8 bh2 = *(const short8*)(ib_hi + (size_t)st * 16 * D_ + ko);
            short8 bl2 = *(const short8*)(ib_lo + (size_t)st * 16 * D_ + ko);
            acc[st] = __builtin_amdgcn_mfma_f32_16x16x32_bf16(al2, bh2, acc[st], 0, 0, 0);
            acc[st] = __builtin_amdgcn_mfma_f32_16x16x32_bf16(ah, bl2, acc[st], 0, 0, 0);
            acc[st] = __builtin_amdgcn_mfma_f32_16x16x32_bf16(ah, bh2, acc[st], 0, 0, 0);
        }
    }
    __syncthreads();
#pragma unroll
    for (int st = 0; st < 4; ++st) {
        int s = s0 + st * 16 + fr;
        float ds = (float)s * (1.0f / S_);
#pragma unroll
        for (int r = 0; r < 4; ++r) {
            int o = o0 + w * 16 + kg * 4 + r;
            float d = ds - (float)o * (1.0f / O_);
            float pf = __expf(-100.0f * d * d);
            float iouv = siou[(st * 16 + fr) * 65 + (w * 16 + kg * 4 + r)];
            KT[((size_t)b * O_ + o) * S_ + s] = pf * (acc[st][r] - iouv) * 10.0f;
        }
    }
}

__global__ __launch_bounds__(256) void row_update2(const float* __restrict__ KT,
                                                   const float* __restrict__ v,
                                                   float* __restrict__ u,
                                                   const int* __restrict__ mask,
                                                   const float* __restrict__ loga) {
    __shared__ float sv[O_];
    __shared__ float lm[4][128], la[4][128];
    int b = blockIdx.y;
    int s0 = blockIdx.x * 128;
    int t = threadIdx.x, lane = t & 63, w = t >> 6;
    for (int i = t; i < O_; i += 256) sv[i] = v[b * O_ + i];
    __syncthreads();
    const float* kt = KT + (size_t)b * O_ * S_ + s0 + lane * 2;
    float m0 = -INFINITY, m1 = -INFINITY, a0 = 0.f, a1 = 0.f;
    int ob = w * 128;
#pragma unroll 8
    for (int i = 0; i < 128; ++i) {
        int o = ob + i;
        float2 x2 = *(const float2*)(kt + (size_t)o * S_);
        float vo = sv[o];
        float x0 = x2.x + vo, x1 = x2.y + vo;
        if (x0 > m0) { a0 = a0 * __expf(m0 - x0) + 1.f; m0 = x0; } else a0 += __expf(x0 - m0);
        if (x1 > m1) { a1 = a1 * __expf(m1 - x1) + 1.f; m1 = x1; } else a1 += __expf(x1 - m1);
    }
    lm[w][lane * 2] = m0;     la[w][lane * 2] = a0;
    lm[w][lane * 2 + 1] = m1; la[w][lane * 2 + 1] = a1;
    __syncthreads();
    if (t < 128) {
        float M = lm[0][t], A = la[0][t];
#pragma unroll
        for (int i = 1; i < 4; ++i) {
            float mi = lm[i][t], ai = la[i][t];
            float nm = fmaxf(M, mi);
            A = A * __expf(M - nm) + ai * __expf(mi - nm);
            M = nm;
        }
        float lse = M + logf(A);
        size_t si = (size_t)b * S_ + s0 + t;
        u[si] = mask[si] ? (loga[b] - u[si] - lse) : NEG_INF_;
    }
}

template <int FIN>
__global__ __launch_bounds__(256) void col_update2(float* __restrict__ KT,
                                                   const float* __restrict__ u,
                                                   float* __restrict__ v) {
    __shared__ float red[8];
    int b = blockIdx.y, o = blockIdx.x;
    int t = threadIdx.x;
    float* kt = KT + ((size_t)b * O_ + o) * S_;
    const float* ub = u + (size_t)b * S_;
    float vold = v[b * O_ + o];
    float xs[16];
    float m = -INFINITY, a = 0.f;
#pragma unroll
    for (int k = 0; k < 4; ++k) {
        int s = k * 1024 + t * 4;
        float4 kx = *(const float4*)(kt + s);
        float4 ux = *(const float4*)(ub + s);
        float x0 = kx.x + ux.x, x1 = kx.y + ux.y, x2 = kx.z + ux.z, x3 = kx.w + ux.w;
        if (FIN) { xs[k*4] = x0; xs[k*4+1] = x1; xs[k*4+2] = x2; xs[k*4+3] = x3; }
        float cm = fmaxf(fmaxf(x0, x1), fmaxf(x2, x3));
        float nm = fmaxf(m, cm);
        a = a * __expf(m - nm) + __expf(x0 - nm) + __expf(x1 - nm)
                               + __expf(x2 - nm) + __expf(x3 - nm);
        m = nm;
    }
#pragma unroll
    for (int off = 1; off < 64; off <<= 1) {
        float mo = __shfl_xor(m, off), ao = __shfl_xor(a, off);
        float nm = fmaxf(m, mo);
        a = a * __expf(m - nm) + ao * __expf(mo - nm);
        m = nm;
    }
    int w = t >> 6;
    if ((t & 63) == 0) { red[w * 2] = m; red[w * 2 + 1] = a; }
    __syncthreads();
    float M = red[0], A = red[1];
#pragma unroll
    for (int i = 1; i < 4; ++i) {
        float mi = red[i * 2], ai = red[i * 2 + 1];
        float nm = fmaxf(M, mi);
        A = A * __expf(M - nm) + ai * __expf(mi - nm);
        M = nm;
    }
    float lse = M + logf(A);
    float vn = -vold - lse;
    if (t == 0) v[b * O_ + o] = vn;
    if (FIN) {
        float oo = (float)o * (1.0f / O_);
#pragma unroll
        for (int k = 0; k < 4; ++k) {
            int s = k * 1024 + t * 4;
            float4 r;
            float rr[4];
#pragma unroll
            for (int j = 0; j < 4; ++j) {
                float d = (float)(s + j) * (1.0f / S_) - oo;
                rr[j] = 4096.0f * __expf(xs[k * 4 + j] + vn - 100.0f * d * d);
            }
            r.x = rr[0]; r.y = rr[1]; r.z = rr[2]; r.w = rr[3];
            *(float4*)(kt + s) = r;
        }
    }
}

// ================= launch =================

extern "C" void kernel_launch(void* const* d_in, const int* in_sizes, int n_in,
                              void* d_out, int out_size, void* d_ws, size_t ws_size,
                              hipStream_t stream) {
    const float* input  = (const float*)d_in[0];
    const float* target = (const float*)d_in[1];
    const float* iou    = (const float*)d_in[2];
    const int*   mask   = (const int*)d_in[3];
    float* out = (float*)d_out;
    float* wsf = (float*)d_ws;

    const size_t N_IN = (size_t)B_ * S_ * D_;   // 8388608
    const size_t N_TG = (size_t)B_ * O_ * D_;   // 1048576
    const size_t NK   = (size_t)B_ * S_ * O_;   // 33554432

    float* u    = wsf;
    float* v    = u + (size_t)B_ * S_;
    float* loga = v + (size_t)B_ * O_;

    float* Knat = loga + 16;
    float* region = Knat + NK;
    unsigned short* f_in_hi = (unsigned short*)region;
    unsigned short* f_in_lo = f_in_hi + N_IN;
    unsigned short* f_tg_hi = f_in_lo + N_IN;
    unsigned short* f_tg_lo = f_tg_hi + N_TG;
    float2* colma = (float2*)region;          // aliases dead split arrays
    size_t need_fast = (size_t)((char*)(f_tg_lo + N_TG) - (char*)d_ws);

    unsigned short* m_in_hi = (unsigned short*)(loga + 16);
    unsigned short* m_in_lo = m_in_hi + N_IN;
    unsigned short* m_tg_hi = m_in_lo + N_IN;
    unsigned short* m_tg_lo = m_tg_hi + N_TG;
    size_t need_mid = (size_t)((char*)(m_tg_lo + N_TG) - (char*)d_ws);

    init_kernel<<<B_, 256, 0, stream>>>(mask, u, v, loga);

    if (ws_size >= need_fast) {
        split_kernel<<<(int)(N_IN / 4 / 256), 256, 0, stream>>>(input, f_in_hi, f_in_lo, (int)(N_IN / 4));
        split_kernel<<<(int)(N_TG / 4 / 256), 256, 0, stream>>>(target, f_tg_hi, f_tg_lo, (int)(N_TG / 4));
        gemm_nat<<<dim3(S_ / 256, O_ / 64, B_), 256, 0, stream>>>(f_in_hi, f_in_lo, f_tg_hi, f_tg_lo, iou, Knat);
        for (int it = 0; it < MAX_ITER_; ++it) {
            if (it == 0)
                sink_iter<1><<<dim3(S_ / 16, B_), 256, 0, stream>>>(Knat, v, u, colma, mask, loga);
            else
                sink_iter<0><<<dim3(S_ / 16, B_), 256, 0, stream>>>(Knat, v, u, colma, mask, loga);
            finalize_v<<<dim3(O_ / 64, B_), 256, 0, stream>>>(colma, v);
        }
        final_tr<<<dim3(S_ / 64, O_ / 64, B_), 256, 0, stream>>>(Knat, u, v, out);
    } else if (ws_size >= need_mid) {
        split_kernel<<<(int)(N_IN / 4 / 256), 256, 0, stream>>>(input, m_in_hi, m_in_lo, (int)(N_IN / 4));
        split_kernel<<<(int)(N_TG / 4 / 256), 256, 0, stream>>>(target, m_tg_hi, m_tg_lo, (int)(N_TG / 4));
        gemm_kt2<<<dim3(S_ / 64, O_ / 64, B_), 256, 0, stream>>>(m_in_hi, m_in_lo, m_tg_hi, m_tg_lo, iou, out);
        for (int it = 0; it < MAX_ITER_; ++it) {
            row_update2<<<dim3(S_ / 128, B_), 256, 0, stream>>>(out, v, u, mask, loga);
            if (it < MAX_ITER_ - 1)
                col_update2<0><<<dim3(O_, B_), 256, 0, stream>>>(out, u, v);
            else
                col_update2<1><<<dim3(O_, B_), 256, 0, stream>>>(out, u, v);
        }
    }
}